// Round 18
// baseline (394.894 us; speedup 1.0000x reference)
//
#include <hip/hip_runtime.h>
#include <hip/hip_fp16.h>

typedef _Float16 f16;
typedef _Float16 f16x4 __attribute__((ext_vector_type(4)));
typedef _Float16 f16x8 __attribute__((ext_vector_type(8)));
typedef float f32x4 __attribute__((ext_vector_type(4)));

#define DEV __device__ __forceinline__

// ---- problem constants ----
constexpr int BB    = 2;
constexpr int LL    = 4096;
constexpr int DM    = 1024;
constexpr int DIN   = 2048;
constexpr int DST   = 128;
constexpr int NH    = 32;
constexpr int HD    = 64;
constexpr int NC    = 64;                  // chunks per batch
constexpr int MROWS = BB * LL;             // 8192
constexpr int NPROJ = 2*DIN + 2*DST + NH;  // 4384 (W_in row stride)
constexpr int NZ    = 2*DIN + 2*DST;       // 4352 (z + xBC, GEMM1 N)
constexpr int CONVD = DIN + 2*DST;         // 2304
constexpr int DT_OFF = 2*DIN + 2*DST;      // 4352
constexpr int BOFF  = DIN;                 // 2048 (within NZ / CONVD)
constexpr int COFF  = DIN + DST;           // 2176

DEV float silu_f(float v) { return v / (1.f + __expf(-v)); }

// wave-uniform LDS dest; HW writes lane i at dst + i*16B. Per-lane global src.
DEV void gload_lds16(const f16* gsrc, f16* lds_dst) {
  __builtin_amdgcn_global_load_lds(
      (const __attribute__((address_space(1))) void*)gsrc,
      (__attribute__((address_space(3))) void*)lds_dst, 16, 0, 0);
}

// ------------- transpose fp32[K rows][srcLd cols] -> fp16[N][K] -------------
// colScale (optional, size K): dst[n][k] = src[k][n] * colScale[k]
__global__ __launch_bounds__(256)
void transpose_f32_to_f16(const float* __restrict__ src, f16* __restrict__ dst,
                          int K, int N, int srcLd, const float* __restrict__ colScale) {
  __shared__ float tbuf[32][33];
  int n0 = blockIdx.x * 32, k0 = blockIdx.y * 32;
  int tx = threadIdx.x & 31, ty = threadIdx.x >> 5;  // 32 x 8
  for (int i = ty; i < 32; i += 8)
    tbuf[i][tx] = src[(size_t)(k0 + i)*srcLd + n0 + tx];
  __syncthreads();
  float cs = colScale ? colScale[k0 + tx] : 1.f;
  for (int i = ty; i < 32; i += 8)
    dst[(size_t)(n0 + i)*K + (k0 + tx)] = (f16)(tbuf[tx][i] * cs);
}

// ------- pipelined MFMA GEMM (R16 proven): C[M][ldc] = A[M][K] * Bt[N][K]^T -------
// 2-buffer LDS, boundary vmcnt(0)+barrier, stage(t+1) before compute(t).
// XCD-chunked swizzle. Optional rowScale. Plateau ~109us / 29.5% MfmaUtil.
template<int BM, int BN, int WM_, int WN_, bool C16>
__global__ __launch_bounds__(WM_*WN_*64, 2)
void gemm_t(const f16* __restrict__ A, const f16* __restrict__ Bt,
            void* __restrict__ Cp, int M, int N, int K, int ldc,
            const float* __restrict__ rowScale) {
  constexpr int THREADS = WM_*WN_*64;
  constexpr int WTM = BM/WM_, WTN = BN/WN_;
  constexpr int FM = WTM/16, FN = WTN/16;
  constexpr int LA = BM*4/THREADS, LB = BN*4/THREADS;  // 16B-chunk loads/thread
  __shared__ f16 As[2][BM*32];
  __shared__ f16 Bs[2][BN*32];
  const int nbn = N / BN;
  const int nwg = (int)gridDim.x;
  const int lb  = ((int)blockIdx.x & 7) * (nwg >> 3) + ((int)blockIdx.x >> 3);
  const int bm = lb / nbn, bn = lb % nbn;
  const int tid = threadIdx.x;
  const int wave = tid >> 6, lane = tid & 63;
  const int lrow = lane & 15, kgrp = lane >> 4;
  const int wm = wave / WN_, wn = wave % WN_;
  const int nt = K >> 5;
  const int bcol8 = (kgrp ^ ((lrow ^ (lrow >> 2)) & 3)) * 8;

  const f16* aptr[LA];
  const f16* bptr[LB];
#pragma unroll
  for (int i = 0; i < LA; ++i) {
    int s = tid + i*THREADS, row = s >> 2;
    int g = (s & 3) ^ ((row ^ (row >> 2)) & 3);
    aptr[i] = A + (size_t)(bm*BM + row)*K + g*8;
  }
#pragma unroll
  for (int i = 0; i < LB; ++i) {
    int s = tid + i*THREADS, row = s >> 2;
    int g = (s & 3) ^ ((row ^ (row >> 2)) & 3);
    bptr[i] = Bt + (size_t)(bn*BN + row)*K + g*8;
  }

  f32x4 acc[FM][FN] = {};

  auto STAGE = [&](int buf, int t) {
#pragma unroll
    for (int i = 0; i < LA; ++i)
      gload_lds16(aptr[i] + (size_t)t*32, As[buf] + (wave*64 + i*THREADS)*8);
#pragma unroll
    for (int i = 0; i < LB; ++i)
      gload_lds16(bptr[i] + (size_t)t*32, Bs[buf] + (wave*64 + i*THREADS)*8);
  };

  STAGE(0, 0);
  asm volatile("s_waitcnt vmcnt(0)" ::: "memory");
  __builtin_amdgcn_s_barrier();
  __builtin_amdgcn_sched_barrier(0);

  for (int t = 0; t < nt; ++t) {
    const int cur = t & 1;
    if (t + 1 < nt) STAGE(cur ^ 1, t + 1);
    const f16* Ab = As[cur];
    const f16* Bb = Bs[cur];
    f16x8 bf[FN];
#pragma unroll
    for (int n = 0; n < FN; ++n)
      bf[n] = *(const f16x8*)(Bb + (wn*WTN + n*16 + lrow)*32 + bcol8);
#pragma unroll
    for (int m = 0; m < FM; ++m) {
      f16x8 af = *(const f16x8*)(Ab + (wm*WTM + m*16 + lrow)*32 + bcol8);
#pragma unroll
      for (int n = 0; n < FN; ++n)
        acc[m][n] = __builtin_amdgcn_mfma_f32_16x16x32_f16(af, bf[n], acc[m][n], 0, 0, 0);
    }
    if (t + 1 < nt) {
      asm volatile("s_waitcnt vmcnt(0)" ::: "memory");
      __builtin_amdgcn_s_barrier();
      __builtin_amdgcn_sched_barrier(0);
    }
  }

  int crow0 = bm*BM + wm*WTM, ccol0 = bn*BN + wn*WTN;
#pragma unroll
  for (int m = 0; m < FM; ++m)
#pragma unroll
    for (int n = 0; n < FN; ++n) {
      int r0 = crow0 + m*16 + (lane >> 4)*4;
      int c0 = ccol0 + n*16 + (lane & 15);
#pragma unroll
      for (int r = 0; r < 4; ++r) {
        float v = acc[m][n][r];
        if (rowScale) v *= rowScale[r0 + r];
        if constexpr (C16) {
          f16* C = (f16*)Cp;
          C[(size_t)(r0 + r)*ldc + c0] = (f16)v;
        } else {
          float* C = (float*)Cp;
          C[(size_t)(r0 + r)*ldc + c0] = v;
        }
      }
    }
}

// ------- exact fp32 dt + fused per-chunk cumsum + fused x->f16 emit -------
__global__ __launch_bounds__(256)
void dt_kernel(const float* __restrict__ x, const float* __restrict__ Win,
               const float* __restrict__ dt_bias, const float* __restrict__ A_log,
               float* __restrict__ dt, float* __restrict__ Acum,
               f16* __restrict__ xh) {
  __shared__ float xs[64][132];
  __shared__ float ws[128][32];
  __shared__ float dts[64][32];
  int bc = blockIdx.x;
  int r0 = bc * 64;
  int t = threadIdx.x;
  int r = t >> 2, c0 = (t & 3) * 8;
  float acc[8] = {};
  for (int kt = 0; kt < 1024; kt += 128) {
    __syncthreads();
#pragma unroll
    for (int i = 0; i < 8; ++i) {
      int idx4 = t + i*256;
      int rr = idx4 >> 5, c4 = (idx4 & 31) * 4;
      f32x4 xv4 = *(const f32x4*)(x + (size_t)(r0 + rr)*1024 + kt + c4);
      *(f32x4*)&xs[rr][c4] = xv4;
      f16x4 xo = {(f16)xv4[0], (f16)xv4[1], (f16)xv4[2], (f16)xv4[3]};
      *(f16x4*)(xh + (size_t)(r0 + rr)*1024 + kt + c4) = xo;
    }
#pragma unroll
    for (int i = 0; i < 4; ++i) {
      int idx4 = t + i*256;
      int rr = idx4 >> 3, c4 = (idx4 & 7) * 4;
      *(f32x4*)&ws[rr][c4] = *(const f32x4*)(Win + (size_t)(kt + rr)*NPROJ + DT_OFF + c4);
    }
    __syncthreads();
#pragma unroll 8
    for (int k = 0; k < 128; ++k) {
      float xv = xs[r][k];
      f32x4 w0 = *(const f32x4*)&ws[k][c0];
      f32x4 w1 = *(const f32x4*)&ws[k][c0 + 4];
#pragma unroll
      for (int j = 0; j < 4; ++j) { acc[j] += xv * w0[j]; acc[4+j] += xv * w1[j]; }
    }
  }
#pragma unroll
  for (int j = 0; j < 8; ++j) {
    float v = acc[j] + dt_bias[c0 + j];
    float sp = (v > 20.f) ? v : log1pf(__expf(v));
    dt[(size_t)(r0 + r)*NH + c0 + j] = sp;
    dts[r][c0 + j] = sp;
  }
  __syncthreads();
  int wave = t >> 6, lane = t & 63;
  for (int hh = 0; hh < 8; ++hh) {
    int h = wave*8 + hh;
    float A = -__expf(A_log[h]);
    float v = A * dts[lane][h];
#pragma unroll
    for (int off = 1; off < 64; off <<= 1) {
      float u = __shfl_up(v, off);
      if (lane >= off) v += u;
    }
    Acum[((size_t)bc*NH + h)*64 + lane] = v;
  }
}

// ---------------- causal depthwise conv (k=4) + bias + silu -> fp16 ----------------
__global__ __launch_bounds__(256)
void conv_kernel(const f16* __restrict__ zxh, const float* __restrict__ cw,
                 const float* __restrict__ cb, f16* __restrict__ out) {
  int i = blockIdx.x * 256 + threadIdx.x;      // MROWS * 288
  int row = i / (CONVD/8);
  int c8  = (i - row*(CONVD/8)) * 8;
  int lb = row & (LL - 1);
  f32x4 a0 = *(const f32x4*)(cb + c8);
  f32x4 a1 = *(const f32x4*)(cb + c8 + 4);
#pragma unroll
  for (int j = 0; j < 4; ++j) {
    int lsrc = lb - 3 + j;
    if (lsrc >= 0) {
      f16x8 v = *(const f16x8*)(zxh + (size_t)(row - 3 + j)*NZ + BOFF + c8);
      f32x4 w0 = *(const f32x4*)(cw + j*CONVD + c8);
      f32x4 w1 = *(const f32x4*)(cw + j*CONVD + c8 + 4);
#pragma unroll
      for (int jj = 0; jj < 4; ++jj) {
        a0[jj] += (float)v[jj]   * w0[jj];
        a1[jj] += (float)v[4+jj] * w1[jj];
      }
    }
  }
  f16x8 o;
#pragma unroll
  for (int jj = 0; jj < 4; ++jj) {
    o[jj]   = (f16)silu_f(a0[jj]);
    o[4+jj] = (f16)silu_f(a1[jj]);
  }
  *(f16x8*)(out + (size_t)row*CONVD + c8) = o;
}

// ---------------- G[bc][l][s] = sum_n C[l,n] * B[s,n] (head-independent, f16 out) ----------------
__global__ __launch_bounds__(256)
void gbuf_kernel(const f16* __restrict__ xbc, f16* __restrict__ G) {
  __shared__ float Cs[64][128];
  __shared__ float Bsm[64][128];
  int bc = blockIdx.x;
  int row0 = bc * 64;
  int t = threadIdx.x;
#pragma unroll
  for (int i = 0; i < 4; ++i) {
    int idx = t + i*256;
    int r = idx >> 4, c8 = (idx & 15) * 8;
    f16x8 cv = *(const f16x8*)(xbc + (size_t)(row0 + r)*CONVD + COFF + c8);
    f16x8 bv = *(const f16x8*)(xbc + (size_t)(row0 + r)*CONVD + BOFF + c8);
    f32x4 c0v = {(float)cv[0], (float)cv[1], (float)cv[2], (float)cv[3]};
    f32x4 c1v = {(float)cv[4], (float)cv[5], (float)cv[6], (float)cv[7]};
    f32x4 b0v = {(float)bv[0], (float)bv[1], (float)bv[2], (float)bv[3]};
    f32x4 b1v = {(float)bv[4], (float)bv[5], (float)bv[6], (float)bv[7]};
    *(f32x4*)&Cs[r][c8]      = c0v;  *(f32x4*)&Cs[r][c8 + 4]  = c1v;
    *(f32x4*)&Bsm[r][c8]     = b0v;  *(f32x4*)&Bsm[r][c8 + 4] = b1v;
  }
  __syncthreads();
  int l0 = (t >> 4)*4, s0 = (t & 15)*4;
  float acc[4][4] = {};
  for (int n4 = 0; n4 < 128; n4 += 4) {
    f32x4 cv[4], bv[4];
#pragma unroll
    for (int i = 0; i < 4; ++i) cv[i] = *(const f32x4*)&Cs[l0 + i][n4];
#pragma unroll
    for (int j = 0; j < 4; ++j) bv[j] = *(const f32x4*)&Bsm[s0 + j][n4];
#pragma unroll
    for (int i = 0; i < 4; ++i)
#pragma unroll
      for (int j = 0; j < 4; ++j)
        acc[i][j] += cv[i][0]*bv[j][0] + cv[i][1]*bv[j][1] + cv[i][2]*bv[j][2] + cv[i][3]*bv[j][3];
  }
#pragma unroll
  for (int i = 0; i < 4; ++i) {
    f16x4 v = {(f16)acc[i][0], (f16)acc[i][1], (f16)acc[i][2], (f16)acc[i][3]};
    *(f16x4*)(G + ((size_t)bc*64 + l0 + i)*64 + s0) = v;
  }
}

// ------- per (bc, head-group of 4): chunk states (MFMA), raw B staged ONCE -------
__global__ __launch_bounds__(256)
void ssd_states_kernel(const f16* __restrict__ xbc, const float* __restrict__ dtb,
                       const float* __restrict__ Acum, f16* __restrict__ states) {
  __shared__ f16 BT[128][72];
  __shared__ f16 XdT[64][72];
  __shared__ float Sl[64][132];
  __shared__ float ac[64], dts[64];
  int bc = blockIdx.x >> 3, hg = blockIdx.x & 7;
  int row0 = bc*64, t = threadIdx.x;
  int wave = t >> 6, lane = t & 63;
  int lrow = lane & 15, kgrp = lane >> 4;
#pragma unroll
  for (int i = 0; i < 4; ++i) {
    int idx = t + i*256; int l = idx >> 4, n8 = (idx & 15)*8;
    f16x8 v = *(const f16x8*)(xbc + (size_t)(row0 + l)*CONVD + BOFF + n8);
#pragma unroll
    for (int j = 0; j < 8; ++j) BT[n8 + j][l] = v[j];
  }
  for (int hh = 0; hh < 4; ++hh) {
    int h = hg*4 + hh;
    __syncthreads();
    if (t < 64) {
      ac[t]  = Acum[((size_t)bc*NH + h)*64 + t];
      dts[t] = dtb[(size_t)(row0 + t)*NH + h];
    }
    __syncthreads();
    float ac63 = ac[63];
#pragma unroll
    for (int i = 0; i < 2; ++i) {
      int idx = t + i*256; int l = idx >> 3, p8 = (idx & 7)*8;
      f16x8 v = *(const f16x8*)(xbc + (size_t)(row0 + l)*CONVD + h*HD + p8);
      float d = dts[l] * __expf(ac63 - ac[l]);
#pragma unroll
      for (int j = 0; j < 8; ++j) XdT[p8 + j][l] = (f16)((float)v[j]*d);
    }
    __syncthreads();
    f32x4 sacc[8] = {};
#pragma unroll
    for (int kk = 0; kk < 64; kk += 32) {
      f16x8 afs = *(const f16x8*)&XdT[wave*16 + lrow][kk + kgrp*8];
#pragma unroll
      for (int n = 0; n < 8; ++n) {
        f16x8 bf = *(const f16x8*)&BT[n*16 + lrow][kk + kgrp*8];
        sacc[n] = __builtin_amdgcn_mfma_f32_16x16x32_f16(afs, bf, sacc[n], 0, 0, 0);
      }
    }
    __syncthreads();
#pragma unroll
    for (int n = 0; n < 8; ++n)
#pragma unroll
      for (int r = 0; r < 4; ++r)
        Sl[wave*16 + kgrp*4 + r][n*16 + lrow] = sacc[n][r];
    __syncthreads();
    size_t sb = ((size_t)bc*NH + h)*8192;
#pragma unroll
    for (int i = 0; i < 4; ++i) {
      int idx = t + i*256; int p = idx >> 4, n8 = (idx & 15)*8;
      f16x8 o;
#pragma unroll
      for (int j = 0; j < 8; ++j) o[j] = (f16)Sl[p][n8 + j];
      *(f16x8*)(states + sb + (size_t)p*128 + n8) = o;
    }
  }
}

// ---------------- inter-chunk scan (in place, fp16 storage, fp32 carry) ----------------
__global__ __launch_bounds__(256)
void scan_kernel(f16* __restrict__ states, const float* __restrict__ Acum) {
  int bid = blockIdx.x;
  int bh = bid >> 3, pgrp = bid & 7;
  int b = bh >> 5, h = bh & 31;
  int t = threadIdx.x;
  int p = pgrp*8 + (t >> 5), n4 = (t & 31) * 4;
  size_t off = (size_t)p*128 + n4;
  f32x4 carry = {0.f, 0.f, 0.f, 0.f};
  for (int c = 0; c < NC; ++c) {
    size_t base = ((size_t)(b*NC + c)*NH + h)*8192;
    f16x4 cv = *(f16x4*)(states + base + off);
    f16x4 st;
#pragma unroll
    for (int j = 0; j < 4; ++j) st[j] = (f16)carry[j];
    *(f16x4*)(states + base + off) = st;
    float tc = __expf(Acum[((size_t)(b*NC + c)*NH + h)*64 + 63]);
#pragma unroll
    for (int j = 0; j < 4; ++j) carry[j] = carry[j]*tc + (float)cv[j];
  }
}

// ------- per (bc, head-group of 4): Y_diag + Y_off + D-skip + gate -------
// C and raw G staged ONCE per block, reused across 4 heads.
__global__ __launch_bounds__(256)
void yoff4_kernel(const f16* __restrict__ xbc, const f16* __restrict__ zxh,
                  const f16* __restrict__ Gg, const f16* __restrict__ states,
                  const float* __restrict__ dtb, const float* __restrict__ Acum,
                  const float* __restrict__ Dp, f16* __restrict__ Ybuf) {
  __shared__ f16 Ch[64][136];    // C, persistent (17.4 KB)
  __shared__ f16 Graw[64][72];   // raw G[l][s], persistent (9.2 KB)
  __shared__ union {
    struct { f16 Gt[64][72]; f16 XdT[64][72]; } a;  // 18.4 KB (ydiag operands)
    f16 Sin[64][136];                               // 17.4 KB (yoff B-operand)
    float Yl2[64][68];                              // 17 KB (yoff retile)
  } u;
  __shared__ float Yl[64][68];   // 17 KB, ydiag fp32, persists per head
  __shared__ float ac[64], dts[64], eac[64];
  int bc = blockIdx.x >> 3, hg = blockIdx.x & 7;
  int row0 = bc*64, t = threadIdx.x;
  int wave = t >> 6, lane = t & 63;
  int lrow = lane & 15, kgrp = lane >> 4;
  // stage persistent C and raw G once
#pragma unroll
  for (int i = 0; i < 4; ++i) {
    int idx = t + i*256; int r = idx >> 4, c8 = (idx & 15)*8;
    *(f16x8*)&Ch[r][c8] = *(const f16x8*)(xbc + (size_t)(row0 + r)*CONVD + COFF + c8);
  }
#pragma unroll
  for (int i = 0; i < 2; ++i) {
    int idx = t + i*256; int l = idx >> 3, s8 = (idx & 7)*8;
    *(f16x8*)&Graw[l][s8] = *(const f16x8*)(Gg + (size_t)bc*4096 + l*64 + s8);
  }
  for (int hh = 0; hh < 4; ++hh) {
    int h = hg*4 + hh;
    __syncthreads();  // prev head's Yl2/epilogue done; (iter0: staging visible)
    if (t < 64) {
      float a0 = Acum[((size_t)bc*NH + h)*64 + t];
      ac[t]  = a0;
      eac[t] = __expf(a0);
      dts[t] = dtb[(size_t)(row0 + t)*NH + h];
    }
    __syncthreads();
    // stage XdT[p][l] = x[l][p]*dt[l]  and  Gt[l][s] from LDS-resident Graw
#pragma unroll
    for (int i = 0; i < 2; ++i) {
      int idx = t + i*256; int l = idx >> 3, p8 = (idx & 7)*8;
      f16x8 v = *(const f16x8*)(xbc + (size_t)(row0 + l)*CONVD + h*HD + p8);
      float d = dts[l];
#pragma unroll
      for (int j = 0; j < 8; ++j) u.a.XdT[p8 + j][l] = (f16)((float)v[j]*d);
    }
#pragma unroll
    for (int i = 0; i < 2; ++i) {
      int idx = t + i*256; int l = idx >> 3, s8 = (idx & 7)*8;
      f16x8 g = *(const f16x8*)&Graw[l][s8];
      float al = ac[l];
      f16x8 o;
#pragma unroll
      for (int j = 0; j < 8; ++j) {
        int s = s8 + j;
        o[j] = (l >= s) ? (f16)((float)g[j] * __expf(al - ac[s])) : (f16)0.f;
      }
      *(f16x8*)&u.a.Gt[l][s8] = o;
    }
    __syncthreads();
    // ydiag MFMA: Y[l][p] = sum_s Gt[l][s] * Xd[s][p]
    f32x4 yacc[4] = {};
#pragma unroll
    for (int kk = 0; kk < 64; kk += 32) {
      f16x8 afy = *(const f16x8*)&u.a.Gt[wave*16 + lrow][kk + kgrp*8];
#pragma unroll
      for (int n = 0; n < 4; ++n) {
        f16x8 bf = *(const f16x8*)&u.a.XdT[n*16 + lrow][kk + kgrp*8];
        yacc[n] = __builtin_amdgcn_mfma_f32_16x16x32_f16(afy, bf, yacc[n], 0, 0, 0);
      }
    }
    __syncthreads();   // u.a reads done -> reuse as Sin
#pragma unroll
    for (int n = 0; n < 4; ++n)
#pragma unroll
      for (int r = 0; r < 4; ++r)
        Yl[wave*16 + kgrp*4 + r][n*16 + lrow] = yacc[n][r];
    size_t sb = ((size_t)bc*NH + h)*8192;
#pragma unroll
    for (int i = 0; i < 4; ++i) {
      int idx = t + i*256; int r = idx >> 4, c8 = (idx & 15)*8;
      *(f16x8*)&u.Sin[r][c8] = *(const f16x8*)(states + sb + (size_t)r*128 + c8);
    }
    __syncthreads();
    // yoff MFMA: yoffraw[l][p] = sum_n C[l][n] * Sin[p][n]
    f32x4 acc[4] = {};
#pragma unroll
    for (int kk = 0; kk < 128; kk += 32) {
      f16x8 af = *(const f16x8*)&Ch[wave*16 + lrow][kk + kgrp*8];
#pragma unroll
      for (int n = 0; n < 4; ++n) {
        f16x8 bf = *(const f16x8*)&u.Sin[n*16 + lrow][kk + kgrp*8];
        acc[n] = __builtin_amdgcn_mfma_f32_16x16x32_f16(af, bf, acc[n], 0, 0, 0);
      }
    }
    __syncthreads();   // Sin reads done -> reuse as Yl2
#pragma unroll
    for (int n = 0; n < 4; ++n)
#pragma unroll
      for (int r = 0; r < 4; ++r)
        u.Yl2[wave*16 + kgrp*4 + r][n*16 + lrow] = acc[n][r];
    __syncthreads();
    // epilogue: Y = (ydiag + eac*yoffraw + D*x) * silu(z); single Ybuf write
    float Dh = Dp[h];
#pragma unroll
    for (int i = 0; i < 2; ++i) {
      int idx = t + i*256; int l = idx >> 3, p8 = (idx & 7)*8;
      int row = row0 + l;
      f16x8 zh = *(const f16x8*)(zxh + (size_t)row*NZ + h*HD + p8);
      f16x8 xs = *(const f16x8*)(xbc + (size_t)row*CONVD + h*HD + p8);
      float e = eac[l];
      f16x8 o;
#pragma unroll
      for (int j = 0; j < 8; ++j) {
        float yv = Yl[l][p8 + j] + e*u.Yl2[l][p8 + j] + (float)xs[j]*Dh;
        o[j] = (f16)(yv * silu_f((float)zh[j]));
      }
      *(f16x8*)(Ybuf + (size_t)row*DIN + h*HD + p8) = o;
    }
  }
}

// ------- RMS scale only: scale[row] = rsqrt(mean(Ybuf[row]^2)+eps) -------
__global__ __launch_bounds__(256)
void rms_scale_kernel(const f16* __restrict__ yg, float* __restrict__ scale) {
  __shared__ float red[4];
  int row = blockIdx.x, t = threadIdx.x;
  f16x8 v = *(const f16x8*)(yg + (size_t)row*DIN + t*8);
  float ss = 0.f;
#pragma unroll
  for (int j = 0; j < 8; ++j) { float f = (float)v[j]; ss += f*f; }
#pragma unroll
  for (int off = 32; off > 0; off >>= 1) ss += __shfl_down(ss, off);
  if ((t & 63) == 0) red[t >> 6] = ss;
  __syncthreads();
  if (t == 0) {
    float tot = red[0] + red[1] + red[2] + red[3];
    scale[row] = rsqrtf(tot * (1.f/2048.f) + 1e-5f);
  }
}

// ---------------- host launcher ----------------
extern "C" void kernel_launch(void* const* d_in, const int* in_sizes, int n_in,
                              void* d_out, int out_size, void* d_ws, size_t ws_size,
                              hipStream_t stream) {
  const float* x       = (const float*)d_in[0];
  const float* W_in    = (const float*)d_in[1];
  const float* conv_w  = (const float*)d_in[2];
  const float* conv_b  = (const float*)d_in[3];
  const float* dt_bias = (const float*)d_in[4];
  const float* A_log   = (const float*)d_in[5];
  const float* Dp      = (const float*)d_in[6];
  const float* norm_w  = (const float*)d_in[7];
  const float* W_out   = (const float*)d_in[8];

  constexpr size_t WS_NEED = 213909504;
  if (ws_size < WS_NEED) return;  // clean fail instead of OOB crash

  char* w = (char*)d_ws;
  f16*   states = (f16*)(w + 0);
  f16*   winT   = (f16*)(w + 0);
  f16*   xh     = (f16*)(w + 33554432);
  f16*   woutT  = (f16*)(w + 33554432);
  f16*   zxh    = (f16*)(w + 67108864);
  f16*   xbcc   = (f16*)(w + 138412032);
  f16*   Ybuf   = (f16*)(w + 176160768);
  float* dtb    = (float*)(w + 209715200);
  float* Acum   = (float*)(w + 210763776);
  f16*   Gg     = (f16*)(w + 211812352);
  float* rscale = (float*)(w + 212860928);   // 32 KB

  dt_kernel<<<MROWS/64, 256, 0, stream>>>(x, W_in, dt_bias, A_log, dtb, Acum, xh);
  transpose_f32_to_f16<<<dim3(NZ/32, DM/32), 256, 0, stream>>>(W_in, winT, DM, NZ, NPROJ, nullptr);
  gemm_t<256,128,4,2,true><<<(MROWS/256)*(NZ/128), 512, 0, stream>>>(xh, winT, zxh, MROWS, NZ, DM, NZ, nullptr);
  conv_kernel<<<MROWS*(CONVD/8)/256, 256, 0, stream>>>(zxh, conv_w, conv_b, xbcc);
  gbuf_kernel<<<BB*NC, 256, 0, stream>>>(xbcc, Gg);
  ssd_states_kernel<<<BB*NC*(NH/4), 256, 0, stream>>>(xbcc, dtb, Acum, states);
  scan_kernel<<<BB*NH*8, 256, 0, stream>>>(states, Acum);
  yoff4_kernel<<<BB*NC*(NH/4), 256, 0, stream>>>(xbcc, zxh, Gg, states, dtb, Acum, Dp, Ybuf);
  transpose_f32_to_f16<<<dim3(DM/32, DIN/32), 256, 0, stream>>>(W_out, woutT, DIN, DM, DM, norm_w);
  rms_scale_kernel<<<MROWS, 256, 0, stream>>>(Ybuf, rscale);
  gemm_t<128,128,2,2,false><<<(MROWS/128)*(DM/128), 256, 0, stream>>>(Ybuf, woutT, d_out, MROWS, DM, DIN, DM, rscale);
}

// Round 19
// 387.598 us; speedup vs baseline: 1.0188x; 1.0188x over previous
//
#include <hip/hip_runtime.h>
#include <hip/hip_fp16.h>

typedef _Float16 f16;
typedef _Float16 f16x4 __attribute__((ext_vector_type(4)));
typedef _Float16 f16x8 __attribute__((ext_vector_type(8)));
typedef float f32x4 __attribute__((ext_vector_type(4)));

#define DEV __device__ __forceinline__

// ---- problem constants ----
constexpr int BB    = 2;
constexpr int LL    = 4096;
constexpr int DM    = 1024;
constexpr int DIN   = 2048;
constexpr int DST   = 128;
constexpr int NH    = 32;
constexpr int HD    = 64;
constexpr int NC    = 64;                  // chunks per batch
constexpr int MROWS = BB * LL;             // 8192
constexpr int NPROJ = 2*DIN + 2*DST + NH;  // 4384 (W_in row stride)
constexpr int NZ    = 2*DIN + 2*DST;       // 4352 (z + xBC, GEMM1 N)
constexpr int CONVD = DIN + 2*DST;         // 2304
constexpr int DT_OFF = 2*DIN + 2*DST;      // 4352
constexpr int BOFF  = DIN;                 // 2048 (within NZ / CONVD)
constexpr int COFF  = DIN + DST;           // 2176

DEV float silu_f(float v) { return v / (1.f + __expf(-v)); }

// wave-uniform LDS dest; HW writes lane i at dst + i*16B. Per-lane global src.
DEV void gload_lds16(const f16* gsrc, f16* lds_dst) {
  __builtin_amdgcn_global_load_lds(
      (const __attribute__((address_space(1))) void*)gsrc,
      (__attribute__((address_space(3))) void*)lds_dst, 16, 0, 0);
}

// ------------- transpose fp32[K rows][srcLd cols] -> fp16[N][K] -------------
// colScale (optional, size K): dst[n][k] = src[k][n] * colScale[k]
__global__ __launch_bounds__(256)
void transpose_f32_to_f16(const float* __restrict__ src, f16* __restrict__ dst,
                          int K, int N, int srcLd, const float* __restrict__ colScale) {
  __shared__ float tbuf[32][33];
  int n0 = blockIdx.x * 32, k0 = blockIdx.y * 32;
  int tx = threadIdx.x & 31, ty = threadIdx.x >> 5;  // 32 x 8
  for (int i = ty; i < 32; i += 8)
    tbuf[i][tx] = src[(size_t)(k0 + i)*srcLd + n0 + tx];
  __syncthreads();
  float cs = colScale ? colScale[k0 + tx] : 1.f;
  for (int i = ty; i < 32; i += 8)
    dst[(size_t)(n0 + i)*K + (k0 + tx)] = (f16)(tbuf[tx][i] * cs);
}

// ------- pipelined MFMA GEMM (R16 proven): C[M][ldc] = A[M][K] * Bt[N][K]^T -------
// 2-buffer LDS, boundary vmcnt(0)+barrier, stage(t+1) before compute(t).
// XCD-chunked swizzle. Optional rowScale. Plateau ~109us / 29.5% MfmaUtil.
template<int BM, int BN, int WM_, int WN_, bool C16>
__global__ __launch_bounds__(WM_*WN_*64, 2)
void gemm_t(const f16* __restrict__ A, const f16* __restrict__ Bt,
            void* __restrict__ Cp, int M, int N, int K, int ldc,
            const float* __restrict__ rowScale) {
  constexpr int THREADS = WM_*WN_*64;
  constexpr int WTM = BM/WM_, WTN = BN/WN_;
  constexpr int FM = WTM/16, FN = WTN/16;
  constexpr int LA = BM*4/THREADS, LB = BN*4/THREADS;  // 16B-chunk loads/thread
  __shared__ f16 As[2][BM*32];
  __shared__ f16 Bs[2][BN*32];
  const int nbn = N / BN;
  const int nwg = (int)gridDim.x;
  const int lb  = ((int)blockIdx.x & 7) * (nwg >> 3) + ((int)blockIdx.x >> 3);
  const int bm = lb / nbn, bn = lb % nbn;
  const int tid = threadIdx.x;
  const int wave = tid >> 6, lane = tid & 63;
  const int lrow = lane & 15, kgrp = lane >> 4;
  const int wm = wave / WN_, wn = wave % WN_;
  const int nt = K >> 5;
  const int bcol8 = (kgrp ^ ((lrow ^ (lrow >> 2)) & 3)) * 8;

  const f16* aptr[LA];
  const f16* bptr[LB];
#pragma unroll
  for (int i = 0; i < LA; ++i) {
    int s = tid + i*THREADS, row = s >> 2;
    int g = (s & 3) ^ ((row ^ (row >> 2)) & 3);
    aptr[i] = A + (size_t)(bm*BM + row)*K + g*8;
  }
#pragma unroll
  for (int i = 0; i < LB; ++i) {
    int s = tid + i*THREADS, row = s >> 2;
    int g = (s & 3) ^ ((row ^ (row >> 2)) & 3);
    bptr[i] = Bt + (size_t)(bn*BN + row)*K + g*8;
  }

  f32x4 acc[FM][FN] = {};

  auto STAGE = [&](int buf, int t) {
#pragma unroll
    for (int i = 0; i < LA; ++i)
      gload_lds16(aptr[i] + (size_t)t*32, As[buf] + (wave*64 + i*THREADS)*8);
#pragma unroll
    for (int i = 0; i < LB; ++i)
      gload_lds16(bptr[i] + (size_t)t*32, Bs[buf] + (wave*64 + i*THREADS)*8);
  };

  STAGE(0, 0);
  asm volatile("s_waitcnt vmcnt(0)" ::: "memory");
  __builtin_amdgcn_s_barrier();
  __builtin_amdgcn_sched_barrier(0);

  for (int t = 0; t < nt; ++t) {
    const int cur = t & 1;
    if (t + 1 < nt) STAGE(cur ^ 1, t + 1);
    const f16* Ab = As[cur];
    const f16* Bb = Bs[cur];
    f16x8 bf[FN];
#pragma unroll
    for (int n = 0; n < FN; ++n)
      bf[n] = *(const f16x8*)(Bb + (wn*WTN + n*16 + lrow)*32 + bcol8);
#pragma unroll
    for (int m = 0; m < FM; ++m) {
      f16x8 af = *(const f16x8*)(Ab + (wm*WTM + m*16 + lrow)*32 + bcol8);
#pragma unroll
      for (int n = 0; n < FN; ++n)
        acc[m][n] = __builtin_amdgcn_mfma_f32_16x16x32_f16(af, bf[n], acc[m][n], 0, 0, 0);
    }
    if (t + 1 < nt) {
      asm volatile("s_waitcnt vmcnt(0)" ::: "memory");
      __builtin_amdgcn_s_barrier();
      __builtin_amdgcn_sched_barrier(0);
    }
  }

  int crow0 = bm*BM + wm*WTM, ccol0 = bn*BN + wn*WTN;
#pragma unroll
  for (int m = 0; m < FM; ++m)
#pragma unroll
    for (int n = 0; n < FN; ++n) {
      int r0 = crow0 + m*16 + (lane >> 4)*4;
      int c0 = ccol0 + n*16 + (lane & 15);
#pragma unroll
      for (int r = 0; r < 4; ++r) {
        float v = acc[m][n][r];
        if (rowScale) v *= rowScale[r0 + r];
        if constexpr (C16) {
          f16* C = (f16*)Cp;
          C[(size_t)(r0 + r)*ldc + c0] = (f16)v;
        } else {
          float* C = (float*)Cp;
          C[(size_t)(r0 + r)*ldc + c0] = v;
        }
      }
    }
}

// ------- exact fp32 dt + fused per-chunk cumsum + fused x->f16 emit -------
// R19: 512 threads (4 outputs/thread) — halves the serial inner GEMM; grid is
// only 128 blocks (chunk-bound via cumsum), so per-block speed is the lever.
__global__ __launch_bounds__(512)
void dt_kernel(const float* __restrict__ x, const float* __restrict__ Win,
               const float* __restrict__ dt_bias, const float* __restrict__ A_log,
               float* __restrict__ dt, float* __restrict__ Acum,
               f16* __restrict__ xh) {
  __shared__ float xs[64][132];
  __shared__ float ws[128][32];
  __shared__ float dts[64][32];
  int bc = blockIdx.x;
  int r0 = bc * 64;
  int t = threadIdx.x;           // 0..511
  int r = t >> 3;                // 0..63
  int c0 = (t & 7) * 4;          // 0..28
  float acc[4] = {};
  for (int kt = 0; kt < 1024; kt += 128) {
    __syncthreads();
#pragma unroll
    for (int i = 0; i < 4; ++i) {
      int idx4 = t + i*512;      // 0..2047 -> 64 rows x 32 col4-groups
      int rr = idx4 >> 5, c4 = (idx4 & 31) * 4;
      f32x4 xv4 = *(const f32x4*)(x + (size_t)(r0 + rr)*1024 + kt + c4);
      *(f32x4*)&xs[rr][c4] = xv4;
      f16x4 xo = {(f16)xv4[0], (f16)xv4[1], (f16)xv4[2], (f16)xv4[3]};
      *(f16x4*)(xh + (size_t)(r0 + rr)*1024 + kt + c4) = xo;
    }
#pragma unroll
    for (int i = 0; i < 2; ++i) {
      int idx4 = t + i*512;      // 0..1023 -> 128 rows x 8 col4-groups
      int rr = idx4 >> 3, c4 = (idx4 & 7) * 4;
      *(f32x4*)&ws[rr][c4] = *(const f32x4*)(Win + (size_t)(kt + rr)*NPROJ + DT_OFF + c4);
    }
    __syncthreads();
#pragma unroll 8
    for (int k = 0; k < 128; ++k) {
      float xv = xs[r][k];
      f32x4 w0 = *(const f32x4*)&ws[k][c0];
#pragma unroll
      for (int j = 0; j < 4; ++j) acc[j] += xv * w0[j];
    }
  }
#pragma unroll
  for (int j = 0; j < 4; ++j) {
    float v = acc[j] + dt_bias[c0 + j];
    float sp = (v > 20.f) ? v : log1pf(__expf(v));
    dt[(size_t)(r0 + r)*NH + c0 + j] = sp;
    dts[r][c0 + j] = sp;
  }
  __syncthreads();
  // fused acum: 8 waves x 4 heads, per-head inclusive cumsum over 64 rows
  int wave = t >> 6, lane = t & 63;
#pragma unroll
  for (int hh = 0; hh < 4; ++hh) {
    int h = wave*4 + hh;
    float A = -__expf(A_log[h]);
    float v = A * dts[lane][h];
#pragma unroll
    for (int off = 1; off < 64; off <<= 1) {
      float u = __shfl_up(v, off);
      if (lane >= off) v += u;
    }
    Acum[((size_t)bc*NH + h)*64 + lane] = v;
  }
}

// ---------------- causal depthwise conv (k=4) + bias + silu -> fp16 ----------------
__global__ __launch_bounds__(256)
void conv_kernel(const f16* __restrict__ zxh, const float* __restrict__ cw,
                 const float* __restrict__ cb, f16* __restrict__ out) {
  int i = blockIdx.x * 256 + threadIdx.x;      // MROWS * 288
  int row = i / (CONVD/8);
  int c8  = (i - row*(CONVD/8)) * 8;
  int lb = row & (LL - 1);
  f32x4 a0 = *(const f32x4*)(cb + c8);
  f32x4 a1 = *(const f32x4*)(cb + c8 + 4);
#pragma unroll
  for (int j = 0; j < 4; ++j) {
    int lsrc = lb - 3 + j;
    if (lsrc >= 0) {
      f16x8 v = *(const f16x8*)(zxh + (size_t)(row - 3 + j)*NZ + BOFF + c8);
      f32x4 w0 = *(const f32x4*)(cw + j*CONVD + c8);
      f32x4 w1 = *(const f32x4*)(cw + j*CONVD + c8 + 4);
#pragma unroll
      for (int jj = 0; jj < 4; ++jj) {
        a0[jj] += (float)v[jj]   * w0[jj];
        a1[jj] += (float)v[4+jj] * w1[jj];
      }
    }
  }
  f16x8 o;
#pragma unroll
  for (int jj = 0; jj < 4; ++jj) {
    o[jj]   = (f16)silu_f(a0[jj]);
    o[4+jj] = (f16)silu_f(a1[jj]);
  }
  *(f16x8*)(out + (size_t)row*CONVD + c8) = o;
}

// ---------------- G[bc][l][s] = sum_n C[l,n] * B[s,n] (head-independent, f16 out) ----------------
__global__ __launch_bounds__(256)
void gbuf_kernel(const f16* __restrict__ xbc, f16* __restrict__ G) {
  __shared__ float Cs[64][128];
  __shared__ float Bsm[64][128];
  int bc = blockIdx.x;
  int row0 = bc * 64;
  int t = threadIdx.x;
#pragma unroll
  for (int i = 0; i < 4; ++i) {
    int idx = t + i*256;
    int r = idx >> 4, c8 = (idx & 15) * 8;
    f16x8 cv = *(const f16x8*)(xbc + (size_t)(row0 + r)*CONVD + COFF + c8);
    f16x8 bv = *(const f16x8*)(xbc + (size_t)(row0 + r)*CONVD + BOFF + c8);
    f32x4 c0v = {(float)cv[0], (float)cv[1], (float)cv[2], (float)cv[3]};
    f32x4 c1v = {(float)cv[4], (float)cv[5], (float)cv[6], (float)cv[7]};
    f32x4 b0v = {(float)bv[0], (float)bv[1], (float)bv[2], (float)bv[3]};
    f32x4 b1v = {(float)bv[4], (float)bv[5], (float)bv[6], (float)bv[7]};
    *(f32x4*)&Cs[r][c8]      = c0v;  *(f32x4*)&Cs[r][c8 + 4]  = c1v;
    *(f32x4*)&Bsm[r][c8]     = b0v;  *(f32x4*)&Bsm[r][c8 + 4] = b1v;
  }
  __syncthreads();
  int l0 = (t >> 4)*4, s0 = (t & 15)*4;
  float acc[4][4] = {};
  for (int n4 = 0; n4 < 128; n4 += 4) {
    f32x4 cv[4], bv[4];
#pragma unroll
    for (int i = 0; i < 4; ++i) cv[i] = *(const f32x4*)&Cs[l0 + i][n4];
#pragma unroll
    for (int j = 0; j < 4; ++j) bv[j] = *(const f32x4*)&Bsm[s0 + j][n4];
#pragma unroll
    for (int i = 0; i < 4; ++i)
#pragma unroll
      for (int j = 0; j < 4; ++j)
        acc[i][j] += cv[i][0]*bv[j][0] + cv[i][1]*bv[j][1] + cv[i][2]*bv[j][2] + cv[i][3]*bv[j][3];
  }
#pragma unroll
  for (int i = 0; i < 4; ++i) {
    f16x4 v = {(f16)acc[i][0], (f16)acc[i][1], (f16)acc[i][2], (f16)acc[i][3]};
    *(f16x4*)(G + ((size_t)bc*64 + l0 + i)*64 + s0) = v;
  }
}

// ------- per (bc, head-group of 4): chunk states (MFMA), raw B staged ONCE -------
__global__ __launch_bounds__(256)
void ssd_states_kernel(const f16* __restrict__ xbc, const float* __restrict__ dtb,
                       const float* __restrict__ Acum, f16* __restrict__ states) {
  __shared__ f16 BT[128][72];
  __shared__ f16 XdT[64][72];
  __shared__ float Sl[64][132];
  __shared__ float ac[64], dts[64];
  int bc = blockIdx.x >> 3, hg = blockIdx.x & 7;
  int row0 = bc*64, t = threadIdx.x;
  int wave = t >> 6, lane = t & 63;
  int lrow = lane & 15, kgrp = lane >> 4;
#pragma unroll
  for (int i = 0; i < 4; ++i) {
    int idx = t + i*256; int l = idx >> 4, n8 = (idx & 15)*8;
    f16x8 v = *(const f16x8*)(xbc + (size_t)(row0 + l)*CONVD + BOFF + n8);
#pragma unroll
    for (int j = 0; j < 8; ++j) BT[n8 + j][l] = v[j];
  }
  for (int hh = 0; hh < 4; ++hh) {
    int h = hg*4 + hh;
    __syncthreads();
    if (t < 64) {
      ac[t]  = Acum[((size_t)bc*NH + h)*64 + t];
      dts[t] = dtb[(size_t)(row0 + t)*NH + h];
    }
    __syncthreads();
    float ac63 = ac[63];
#pragma unroll
    for (int i = 0; i < 2; ++i) {
      int idx = t + i*256; int l = idx >> 3, p8 = (idx & 7)*8;
      f16x8 v = *(const f16x8*)(xbc + (size_t)(row0 + l)*CONVD + h*HD + p8);
      float d = dts[l] * __expf(ac63 - ac[l]);
#pragma unroll
      for (int j = 0; j < 8; ++j) XdT[p8 + j][l] = (f16)((float)v[j]*d);
    }
    __syncthreads();
    f32x4 sacc[8] = {};
#pragma unroll
    for (int kk = 0; kk < 64; kk += 32) {
      f16x8 afs = *(const f16x8*)&XdT[wave*16 + lrow][kk + kgrp*8];
#pragma unroll
      for (int n = 0; n < 8; ++n) {
        f16x8 bf = *(const f16x8*)&BT[n*16 + lrow][kk + kgrp*8];
        sacc[n] = __builtin_amdgcn_mfma_f32_16x16x32_f16(afs, bf, sacc[n], 0, 0, 0);
      }
    }
    __syncthreads();
#pragma unroll
    for (int n = 0; n < 8; ++n)
#pragma unroll
      for (int r = 0; r < 4; ++r)
        Sl[wave*16 + kgrp*4 + r][n*16 + lrow] = sacc[n][r];
    __syncthreads();
    size_t sb = ((size_t)bc*NH + h)*8192;
#pragma unroll
    for (int i = 0; i < 4; ++i) {
      int idx = t + i*256; int p = idx >> 4, n8 = (idx & 15)*8;
      f16x8 o;
#pragma unroll
      for (int j = 0; j < 8; ++j) o[j] = (f16)Sl[p][n8 + j];
      *(f16x8*)(states + sb + (size_t)p*128 + n8) = o;
    }
  }
}

// ---------------- inter-chunk scan (in place, fp16 storage, fp32 carry) ----------------
__global__ __launch_bounds__(256)
void scan_kernel(f16* __restrict__ states, const float* __restrict__ Acum) {
  int bid = blockIdx.x;
  int bh = bid >> 3, pgrp = bid & 7;
  int b = bh >> 5, h = bh & 31;
  int t = threadIdx.x;
  int p = pgrp*8 + (t >> 5), n4 = (t & 31) * 4;
  size_t off = (size_t)p*128 + n4;
  f32x4 carry = {0.f, 0.f, 0.f, 0.f};
  for (int c = 0; c < NC; ++c) {
    size_t base = ((size_t)(b*NC + c)*NH + h)*8192;
    f16x4 cv = *(f16x4*)(states + base + off);
    f16x4 st;
#pragma unroll
    for (int j = 0; j < 4; ++j) st[j] = (f16)carry[j];
    *(f16x4*)(states + base + off) = st;
    float tc = __expf(Acum[((size_t)(b*NC + c)*NH + h)*64 + 63]);
#pragma unroll
    for (int j = 0; j < 4; ++j) carry[j] = carry[j]*tc + (float)cv[j];
  }
}

// ------- per (b,c,h): Y_diag + Y_off + D-skip + SiLU(z) gating, Ybuf written ONCE -------
__global__ __launch_bounds__(256)
void yoff_kernel(const f16* __restrict__ xbc, const f16* __restrict__ zxh,
                 const f16* __restrict__ Gg, const f16* __restrict__ states,
                 const float* __restrict__ dtb, const float* __restrict__ Acum,
                 const float* __restrict__ Dp, f16* __restrict__ Ybuf) {
  __shared__ union {
    struct { f16 Gt[64][72]; f16 XdT[64][72]; } a;   // 18 KB (ydiag operands)
    struct { f16 Ch[64][136]; f16 Sin[64][136]; } b; // 34 KB (yoff operands)
    float Yl2[64][68];                               // 17 KB (yoff retile)
  } u;
  __shared__ float Yl[64][68];   // 17 KB, ydiag fp32, persists
  __shared__ float ac[64], dts[64], eac[64];
  int bc = blockIdx.x >> 5, h = blockIdx.x & 31;
  int row0 = bc*64, t = threadIdx.x;
  if (t < 64) {
    float a0 = Acum[((size_t)bc*NH + h)*64 + t];
    ac[t]  = a0;
    eac[t] = __expf(a0);
    dts[t] = dtb[(size_t)(row0 + t)*NH + h];
  }
  __syncthreads();
  // stage XdT[p][l] = x[l][p]*dt[l]
#pragma unroll
  for (int i = 0; i < 2; ++i) {
    int idx = t + i*256; int l = idx >> 3, p8 = (idx & 7)*8;
    f16x8 v = *(const f16x8*)(xbc + (size_t)(row0 + l)*CONVD + h*HD + p8);
    float d = dts[l];
#pragma unroll
    for (int j = 0; j < 8; ++j) u.a.XdT[p8 + j][l] = (f16)((float)v[j]*d);
  }
  // stage Gt[l][s] = (l>=s) ? G[l][s]*exp(ac[l]-ac[s]) : 0
#pragma unroll
  for (int i = 0; i < 2; ++i) {
    int idx = t + i*256; int l = idx >> 3, s8 = (idx & 7)*8;
    f16x8 g = *(const f16x8*)(Gg + (size_t)bc*4096 + l*64 + s8);
    float al = ac[l];
    f16x8 o;
#pragma unroll
    for (int j = 0; j < 8; ++j) {
      int s = s8 + j;
      o[j] = (l >= s) ? (f16)((float)g[j] * __expf(al - ac[s])) : (f16)0.f;
    }
    *(f16x8*)&u.a.Gt[l][s8] = o;
  }
  __syncthreads();
  int wave = t >> 6, lane = t & 63;
  int lrow = lane & 15, kgrp = lane >> 4;
  // ydiag MFMA: Y[l][p] = sum_s Gt[l][s] * Xd[s][p]
  f32x4 yacc[4] = {};
#pragma unroll
  for (int kk = 0; kk < 64; kk += 32) {
    f16x8 afy = *(const f16x8*)&u.a.Gt[wave*16 + lrow][kk + kgrp*8];
#pragma unroll
    for (int n = 0; n < 4; ++n) {
      f16x8 bf = *(const f16x8*)&u.a.XdT[n*16 + lrow][kk + kgrp*8];
      yacc[n] = __builtin_amdgcn_mfma_f32_16x16x32_f16(afy, bf, yacc[n], 0, 0, 0);
    }
  }
  __syncthreads();   // union.a reads done -> safe to reuse as union.b
  // retile ydiag into persistent fp32 Yl
#pragma unroll
  for (int n = 0; n < 4; ++n)
#pragma unroll
    for (int r = 0; r < 4; ++r)
      Yl[wave*16 + kgrp*4 + r][n*16 + lrow] = yacc[n][r];
  // stage Ch (C) and Sin (scanned states) into union.b
  size_t sb = ((size_t)bc*NH + h)*8192;
#pragma unroll
  for (int i = 0; i < 4; ++i) {
    int idx = t + i*256; int r = idx >> 4, c8 = (idx & 15)*8;
    *(f16x8*)&u.b.Ch[r][c8]  = *(const f16x8*)(xbc + (size_t)(row0 + r)*CONVD + COFF + c8);
    *(f16x8*)&u.b.Sin[r][c8] = *(const f16x8*)(states + sb + (size_t)r*128 + c8);
  }
  __syncthreads();
  // yoff MFMA: yoffraw[l][p] = sum_n C[l][n] * Sin[p][n]
  f32x4 acc[4] = {};
#pragma unroll
  for (int kk = 0; kk < 128; kk += 32) {
    f16x8 af = *(const f16x8*)&u.b.Ch[wave*16 + lrow][kk + kgrp*8];
#pragma unroll
    for (int n = 0; n < 4; ++n) {
      f16x8 bf = *(const f16x8*)&u.b.Sin[n*16 + lrow][kk + kgrp*8];
      acc[n] = __builtin_amdgcn_mfma_f32_16x16x32_f16(af, bf, acc[n], 0, 0, 0);
    }
  }
  __syncthreads();   // union.b reads done -> safe to reuse as Yl2
#pragma unroll
  for (int n = 0; n < 4; ++n)
#pragma unroll
    for (int r = 0; r < 4; ++r)
      u.Yl2[wave*16 + kgrp*4 + r][n*16 + lrow] = acc[n][r];
  __syncthreads();
  // epilogue: Y = (ydiag + eac*yoffraw + D*x) * silu(z); single Ybuf write
  float Dh = Dp[h];
#pragma unroll
  for (int i = 0; i < 2; ++i) {
    int idx = t + i*256; int l = idx >> 3, p8 = (idx & 7)*8;
    int row = row0 + l;
    f16x8 zh = *(const f16x8*)(zxh + (size_t)row*NZ + h*HD + p8);
    f16x8 xs = *(const f16x8*)(xbc + (size_t)row*CONVD + h*HD + p8);
    float e = eac[l];
    f16x8 o;
#pragma unroll
    for (int j = 0; j < 8; ++j) {
      float yv = Yl[l][p8 + j] + e*u.Yl2[l][p8 + j] + (float)xs[j]*Dh;
      o[j] = (f16)(yv * silu_f((float)zh[j]));
    }
    *(f16x8*)(Ybuf + (size_t)row*DIN + h*HD + p8) = o;
  }
}

// ------- RMS scale only: scale[row] = rsqrt(mean(Ybuf[row]^2)+eps) -------
__global__ __launch_bounds__(256)
void rms_scale_kernel(const f16* __restrict__ yg, float* __restrict__ scale) {
  __shared__ float red[4];
  int row = blockIdx.x, t = threadIdx.x;
  f16x8 v = *(const f16x8*)(yg + (size_t)row*DIN + t*8);
  float ss = 0.f;
#pragma unroll
  for (int j = 0; j < 8; ++j) { float f = (float)v[j]; ss += f*f; }
#pragma unroll
  for (int off = 32; off > 0; off >>= 1) ss += __shfl_down(ss, off);
  if ((t & 63) == 0) red[t >> 6] = ss;
  __syncthreads();
  if (t == 0) {
    float tot = red[0] + red[1] + red[2] + red[3];
    scale[row] = rsqrtf(tot * (1.f/2048.f) + 1e-5f);
  }
}

// ---------------- host launcher ----------------
extern "C" void kernel_launch(void* const* d_in, const int* in_sizes, int n_in,
                              void* d_out, int out_size, void* d_ws, size_t ws_size,
                              hipStream_t stream) {
  const float* x       = (const float*)d_in[0];
  const float* W_in    = (const float*)d_in[1];
  const float* conv_w  = (const float*)d_in[2];
  const float* conv_b  = (const float*)d_in[3];
  const float* dt_bias = (const float*)d_in[4];
  const float* A_log   = (const float*)d_in[5];
  const float* Dp      = (const float*)d_in[6];
  const float* norm_w  = (const float*)d_in[7];
  const float* W_out   = (const float*)d_in[8];

  constexpr size_t WS_NEED = 213909504;
  if (ws_size < WS_NEED) return;  // clean fail instead of OOB crash

  char* w = (char*)d_ws;
  f16*   states = (f16*)(w + 0);
  f16*   winT   = (f16*)(w + 0);
  f16*   xh     = (f16*)(w + 33554432);
  f16*   woutT  = (f16*)(w + 33554432);
  f16*   zxh    = (f16*)(w + 67108864);
  f16*   xbcc   = (f16*)(w + 138412032);
  f16*   Ybuf   = (f16*)(w + 176160768);
  float* dtb    = (float*)(w + 209715200);
  float* Acum   = (float*)(w + 210763776);
  f16*   Gg     = (f16*)(w + 211812352);
  float* rscale = (float*)(w + 212860928);   // 32 KB

  dt_kernel<<<MROWS/64, 512, 0, stream>>>(x, W_in, dt_bias, A_log, dtb, Acum, xh);
  transpose_f32_to_f16<<<dim3(NZ/32, DM/32), 256, 0, stream>>>(W_in, winT, DM, NZ, NPROJ, nullptr);
  gemm_t<256,128,4,2,true><<<(MROWS/256)*(NZ/128), 512, 0, stream>>>(xh, winT, zxh, MROWS, NZ, DM, NZ, nullptr);
  conv_kernel<<<MROWS*(CONVD/8)/256, 256, 0, stream>>>(zxh, conv_w, conv_b, xbcc);
  gbuf_kernel<<<BB*NC, 256, 0, stream>>>(xbcc, Gg);
  ssd_states_kernel<<<BB*NC*(NH/4), 256, 0, stream>>>(xbcc, dtb, Acum, states);
  scan_kernel<<<BB*NH*8, 256, 0, stream>>>(states, Acum);
  yoff_kernel<<<BB*NC*NH, 256, 0, stream>>>(xbcc, zxh, Gg, states, dtb, Acum, Dp, Ybuf);
  transpose_f32_to_f16<<<dim3(DM/32, DIN/32), 256, 0, stream>>>(W_out, woutT, DIN, DM, DM, norm_w);
  rms_scale_kernel<<<MROWS, 256, 0, stream>>>(Ybuf, rscale);
  gemm_t<128,128,2,2,false><<<(MROWS/128)*(DM/128), 256, 0, stream>>>(Ybuf, woutT, d_out, MROWS, DM, DIN, DM, rscale);
}

// Round 21
// 386.233 us; speedup vs baseline: 1.0224x; 1.0035x over previous
//
#include <hip/hip_runtime.h>
#include <hip/hip_fp16.h>

typedef _Float16 f16;
typedef _Float16 f16x4 __attribute__((ext_vector_type(4)));
typedef _Float16 f16x8 __attribute__((ext_vector_type(8)));
typedef float f32x4 __attribute__((ext_vector_type(4)));

#define DEV __device__ __forceinline__

// ---- problem constants ----
constexpr int BB    = 2;
constexpr int LL    = 4096;
constexpr int DM    = 1024;
constexpr int DIN   = 2048;
constexpr int DST   = 128;
constexpr int NH    = 32;
constexpr int HD    = 64;
constexpr int NC    = 64;                  // chunks per batch
constexpr int MROWS = BB * LL;             // 8192
constexpr int NPROJ = 2*DIN + 2*DST + NH;  // 4384 (W_in row stride)
constexpr int NZ    = 2*DIN + 2*DST;       // 4352 (z + xBC, GEMM1 N)
constexpr int CONVD = DIN + 2*DST;         // 2304
constexpr int DT_OFF = 2*DIN + 2*DST;      // 4352
constexpr int BOFF  = DIN;                 // 2048 (within NZ / CONVD)
constexpr int COFF  = DIN + DST;           // 2176

DEV float silu_f(float v) { return v / (1.f + __expf(-v)); }

// wave-uniform LDS dest; HW writes lane i at dst + i*16B. Per-lane global src.
DEV void gload_lds16(const f16* gsrc, f16* lds_dst) {
  __builtin_amdgcn_global_load_lds(
      (const __attribute__((address_space(1))) void*)gsrc,
      (__attribute__((address_space(3))) void*)lds_dst, 16, 0, 0);
}

// ------------- transpose fp32[K rows][srcLd cols] -> fp16[N][K] -------------
// colScale (optional, size K): dst[n][k] = src[k][n] * colScale[k]
__global__ __launch_bounds__(256)
void transpose_f32_to_f16(const float* __restrict__ src, f16* __restrict__ dst,
                          int K, int N, int srcLd, const float* __restrict__ colScale) {
  __shared__ float tbuf[32][33];
  int n0 = blockIdx.x * 32, k0 = blockIdx.y * 32;
  int tx = threadIdx.x & 31, ty = threadIdx.x >> 5;  // 32 x 8
  for (int i = ty; i < 32; i += 8)
    tbuf[i][tx] = src[(size_t)(k0 + i)*srcLd + n0 + tx];
  __syncthreads();
  float cs = colScale ? colScale[k0 + tx] : 1.f;
  for (int i = ty; i < 32; i += 8)
    dst[(size_t)(n0 + i)*K + (k0 + tx)] = (f16)(tbuf[tx][i] * cs);
}

// ------- pipelined MFMA GEMM (R16 proven): C[M][ldc] = A[M][K] * Bt[N][K]^T -------
// 2-buffer LDS, boundary vmcnt(0)+barrier, stage(t+1) before compute(t).
// XCD-chunked swizzle. Optional rowScale. Plateau ~109us / 29.5% MfmaUtil.
template<int BM, int BN, int WM_, int WN_, bool C16>
__global__ __launch_bounds__(WM_*WN_*64, 2)
void gemm_t(const f16* __restrict__ A, const f16* __restrict__ Bt,
            void* __restrict__ Cp, int M, int N, int K, int ldc,
            const float* __restrict__ rowScale) {
  constexpr int THREADS = WM_*WN_*64;
  constexpr int WTM = BM/WM_, WTN = BN/WN_;
  constexpr int FM = WTM/16, FN = WTN/16;
  constexpr int LA = BM*4/THREADS, LB = BN*4/THREADS;  // 16B-chunk loads/thread
  __shared__ f16 As[2][BM*32];
  __shared__ f16 Bs[2][BN*32];
  const int nbn = N / BN;
  const int nwg = (int)gridDim.x;
  const int lb  = ((int)blockIdx.x & 7) * (nwg >> 3) + ((int)blockIdx.x >> 3);
  const int bm = lb / nbn, bn = lb % nbn;
  const int tid = threadIdx.x;
  const int wave = tid >> 6, lane = tid & 63;
  const int lrow = lane & 15, kgrp = lane >> 4;
  const int wm = wave / WN_, wn = wave % WN_;
  const int nt = K >> 5;
  const int bcol8 = (kgrp ^ ((lrow ^ (lrow >> 2)) & 3)) * 8;

  const f16* aptr[LA];
  const f16* bptr[LB];
#pragma unroll
  for (int i = 0; i < LA; ++i) {
    int s = tid + i*THREADS, row = s >> 2;
    int g = (s & 3) ^ ((row ^ (row >> 2)) & 3);
    aptr[i] = A + (size_t)(bm*BM + row)*K + g*8;
  }
#pragma unroll
  for (int i = 0; i < LB; ++i) {
    int s = tid + i*THREADS, row = s >> 2;
    int g = (s & 3) ^ ((row ^ (row >> 2)) & 3);
    bptr[i] = Bt + (size_t)(bn*BN + row)*K + g*8;
  }

  f32x4 acc[FM][FN] = {};

  auto STAGE = [&](int buf, int t) {
#pragma unroll
    for (int i = 0; i < LA; ++i)
      gload_lds16(aptr[i] + (size_t)t*32, As[buf] + (wave*64 + i*THREADS)*8);
#pragma unroll
    for (int i = 0; i < LB; ++i)
      gload_lds16(bptr[i] + (size_t)t*32, Bs[buf] + (wave*64 + i*THREADS)*8);
  };

  STAGE(0, 0);
  asm volatile("s_waitcnt vmcnt(0)" ::: "memory");
  __builtin_amdgcn_s_barrier();
  __builtin_amdgcn_sched_barrier(0);

  for (int t = 0; t < nt; ++t) {
    const int cur = t & 1;
    if (t + 1 < nt) STAGE(cur ^ 1, t + 1);
    const f16* Ab = As[cur];
    const f16* Bb = Bs[cur];
    f16x8 bf[FN];
#pragma unroll
    for (int n = 0; n < FN; ++n)
      bf[n] = *(const f16x8*)(Bb + (wn*WTN + n*16 + lrow)*32 + bcol8);
#pragma unroll
    for (int m = 0; m < FM; ++m) {
      f16x8 af = *(const f16x8*)(Ab + (wm*WTM + m*16 + lrow)*32 + bcol8);
#pragma unroll
      for (int n = 0; n < FN; ++n)
        acc[m][n] = __builtin_amdgcn_mfma_f32_16x16x32_f16(af, bf[n], acc[m][n], 0, 0, 0);
    }
    if (t + 1 < nt) {
      asm volatile("s_waitcnt vmcnt(0)" ::: "memory");
      __builtin_amdgcn_s_barrier();
      __builtin_amdgcn_sched_barrier(0);
    }
  }

  int crow0 = bm*BM + wm*WTM, ccol0 = bn*BN + wn*WTN;
#pragma unroll
  for (int m = 0; m < FM; ++m)
#pragma unroll
    for (int n = 0; n < FN; ++n) {
      int r0 = crow0 + m*16 + (lane >> 4)*4;
      int c0 = ccol0 + n*16 + (lane & 15);
#pragma unroll
      for (int r = 0; r < 4; ++r) {
        float v = acc[m][n][r];
        if (rowScale) v *= rowScale[r0 + r];
        if constexpr (C16) {
          f16* C = (f16*)Cp;
          C[(size_t)(r0 + r)*ldc + c0] = (f16)v;
        } else {
          float* C = (float*)Cp;
          C[(size_t)(r0 + r)*ldc + c0] = v;
        }
      }
    }
}

// ------- exact fp32 dt + fused per-chunk cumsum + fused x->f16 emit -------
// 512 threads (4 outputs/thread); grid 128 blocks (chunk-bound via cumsum).
__global__ __launch_bounds__(512)
void dt_kernel(const float* __restrict__ x, const float* __restrict__ Win,
               const float* __restrict__ dt_bias, const float* __restrict__ A_log,
               float* __restrict__ dt, float* __restrict__ Acum,
               f16* __restrict__ xh) {
  __shared__ float xs[64][132];
  __shared__ float ws[128][32];
  __shared__ float dts[64][32];
  int bc = blockIdx.x;
  int r0 = bc * 64;
  int t = threadIdx.x;           // 0..511
  int r = t >> 3;                // 0..63
  int c0 = (t & 7) * 4;          // 0..28
  float acc[4] = {};
  for (int kt = 0; kt < 1024; kt += 128) {
    __syncthreads();
#pragma unroll
    for (int i = 0; i < 4; ++i) {
      int idx4 = t + i*512;      // 0..2047 -> 64 rows x 32 col4-groups
      int rr = idx4 >> 5, c4 = (idx4 & 31) * 4;
      f32x4 xv4 = *(const f32x4*)(x + (size_t)(r0 + rr)*1024 + kt + c4);
      *(f32x4*)&xs[rr][c4] = xv4;
      f16x4 xo = {(f16)xv4[0], (f16)xv4[1], (f16)xv4[2], (f16)xv4[3]};
      *(f16x4*)(xh + (size_t)(r0 + rr)*1024 + kt + c4) = xo;
    }
#pragma unroll
    for (int i = 0; i < 2; ++i) {
      int idx4 = t + i*512;      // 0..1023 -> 128 rows x 8 col4-groups
      int rr = idx4 >> 3, c4 = (idx4 & 7) * 4;
      *(f32x4*)&ws[rr][c4] = *(const f32x4*)(Win + (size_t)(kt + rr)*NPROJ + DT_OFF + c4);
    }
    __syncthreads();
#pragma unroll 8
    for (int k = 0; k < 128; ++k) {
      float xv = xs[r][k];
      f32x4 w0 = *(const f32x4*)&ws[k][c0];
#pragma unroll
      for (int j = 0; j < 4; ++j) acc[j] += xv * w0[j];
    }
  }
#pragma unroll
  for (int j = 0; j < 4; ++j) {
    float v = acc[j] + dt_bias[c0 + j];
    float sp = (v > 20.f) ? v : log1pf(__expf(v));
    dt[(size_t)(r0 + r)*NH + c0 + j] = sp;
    dts[r][c0 + j] = sp;
  }
  __syncthreads();
  // fused acum: 8 waves x 4 heads, per-head inclusive cumsum over 64 rows
  int wave = t >> 6, lane = t & 63;
#pragma unroll
  for (int hh = 0; hh < 4; ++hh) {
    int h = wave*4 + hh;
    float A = -__expf(A_log[h]);
    float v = A * dts[lane][h];
#pragma unroll
    for (int off = 1; off < 64; off <<= 1) {
      float u = __shfl_up(v, off);
      if (lane >= off) v += u;
    }
    Acum[((size_t)bc*NH + h)*64 + lane] = v;
  }
}

// ---------------- causal depthwise conv (k=4) + bias + silu -> fp16 ----------------
__global__ __launch_bounds__(256)
void conv_kernel(const f16* __restrict__ zxh, const float* __restrict__ cw,
                 const float* __restrict__ cb, f16* __restrict__ out) {
  int i = blockIdx.x * 256 + threadIdx.x;      // MROWS * 288
  int row = i / (CONVD/8);
  int c8  = (i - row*(CONVD/8)) * 8;
  int lb = row & (LL - 1);
  f32x4 a0 = *(const f32x4*)(cb + c8);
  f32x4 a1 = *(const f32x4*)(cb + c8 + 4);
#pragma unroll
  for (int j = 0; j < 4; ++j) {
    int lsrc = lb - 3 + j;
    if (lsrc >= 0) {
      f16x8 v = *(const f16x8*)(zxh + (size_t)(row - 3 + j)*NZ + BOFF + c8);
      f32x4 w0 = *(const f32x4*)(cw + j*CONVD + c8);
      f32x4 w1 = *(const f32x4*)(cw + j*CONVD + c8 + 4);
#pragma unroll
      for (int jj = 0; jj < 4; ++jj) {
        a0[jj] += (float)v[jj]   * w0[jj];
        a1[jj] += (float)v[4+jj] * w1[jj];
      }
    }
  }
  f16x8 o;
#pragma unroll
  for (int jj = 0; jj < 4; ++jj) {
    o[jj]   = (f16)silu_f(a0[jj]);
    o[4+jj] = (f16)silu_f(a1[jj]);
  }
  *(f16x8*)(out + (size_t)row*CONVD + c8) = o;
}

// ---------------- G[bc][l][s] = sum_n C[l,n] * B[s,n] (head-independent, f16 out) ----------------
__global__ __launch_bounds__(256)
void gbuf_kernel(const f16* __restrict__ xbc, f16* __restrict__ G) {
  __shared__ float Cs[64][128];
  __shared__ float Bsm[64][128];
  int bc = blockIdx.x;
  int row0 = bc * 64;
  int t = threadIdx.x;
#pragma unroll
  for (int i = 0; i < 4; ++i) {
    int idx = t + i*256;
    int r = idx >> 4, c8 = (idx & 15) * 8;
    f16x8 cv = *(const f16x8*)(xbc + (size_t)(row0 + r)*CONVD + COFF + c8);
    f16x8 bv = *(const f16x8*)(xbc + (size_t)(row0 + r)*CONVD + BOFF + c8);
    f32x4 c0v = {(float)cv[0], (float)cv[1], (float)cv[2], (float)cv[3]};
    f32x4 c1v = {(float)cv[4], (float)cv[5], (float)cv[6], (float)cv[7]};
    f32x4 b0v = {(float)bv[0], (float)bv[1], (float)bv[2], (float)bv[3]};
    f32x4 b1v = {(float)bv[4], (float)bv[5], (float)bv[6], (float)bv[7]};
    *(f32x4*)&Cs[r][c8]      = c0v;  *(f32x4*)&Cs[r][c8 + 4]  = c1v;
    *(f32x4*)&Bsm[r][c8]     = b0v;  *(f32x4*)&Bsm[r][c8 + 4] = b1v;
  }
  __syncthreads();
  int l0 = (t >> 4)*4, s0 = (t & 15)*4;
  float acc[4][4] = {};
  for (int n4 = 0; n4 < 128; n4 += 4) {
    f32x4 cv[4], bv[4];
#pragma unroll
    for (int i = 0; i < 4; ++i) cv[i] = *(const f32x4*)&Cs[l0 + i][n4];
#pragma unroll
    for (int j = 0; j < 4; ++j) bv[j] = *(const f32x4*)&Bsm[s0 + j][n4];
#pragma unroll
    for (int i = 0; i < 4; ++i)
#pragma unroll
      for (int j = 0; j < 4; ++j)
        acc[i][j] += cv[i][0]*bv[j][0] + cv[i][1]*bv[j][1] + cv[i][2]*bv[j][2] + cv[i][3]*bv[j][3];
  }
#pragma unroll
  for (int i = 0; i < 4; ++i) {
    f16x4 v = {(f16)acc[i][0], (f16)acc[i][1], (f16)acc[i][2], (f16)acc[i][3]};
    *(f16x4*)(G + ((size_t)bc*64 + l0 + i)*64 + s0) = v;
  }
}

// ------- per (bc, head-group of 4): chunk states (MFMA), raw B staged ONCE -------
__global__ __launch_bounds__(256)
void ssd_states_kernel(const f16* __restrict__ xbc, const float* __restrict__ dtb,
                       const float* __restrict__ Acum, f16* __restrict__ states) {
  __shared__ f16 BT[128][72];
  __shared__ f16 XdT[64][72];
  __shared__ float Sl[64][132];
  __shared__ float ac[64], dts[64];
  int bc = blockIdx.x >> 3, hg = blockIdx.x & 7;
  int row0 = bc*64, t = threadIdx.x;
  int wave = t >> 6, lane = t & 63;
  int lrow = lane & 15, kgrp = lane >> 4;
#pragma unroll
  for (int i = 0; i < 4; ++i) {
    int idx = t + i*256; int l = idx >> 4, n8 = (idx & 15)*8;
    f16x8 v = *(const f16x8*)(xbc + (size_t)(row0 + l)*CONVD + BOFF + n8);
#pragma unroll
    for (int j = 0; j < 8; ++j) BT[n8 + j][l] = v[j];
  }
  for (int hh = 0; hh < 4; ++hh) {
    int h = hg*4 + hh;
    __syncthreads();
    if (t < 64) {
      ac[t]  = Acum[((size_t)bc*NH + h)*64 + t];
      dts[t] = dtb[(size_t)(row0 + t)*NH + h];
    }
    __syncthreads();
    float ac63 = ac[63];
#pragma unroll
    for (int i = 0; i < 2; ++i) {
      int idx = t + i*256; int l = idx >> 3, p8 = (idx & 7)*8;
      f16x8 v = *(const f16x8*)(xbc + (size_t)(row0 + l)*CONVD + h*HD + p8);
      float d = dts[l] * __expf(ac63 - ac[l]);
#pragma unroll
      for (int j = 0; j < 8; ++j) XdT[p8 + j][l] = (f16)((float)v[j]*d);
    }
    __syncthreads();
    f32x4 sacc[8] = {};
#pragma unroll
    for (int kk = 0; kk < 64; kk += 32) {
      f16x8 afs = *(const f16x8*)&XdT[wave*16 + lrow][kk + kgrp*8];
#pragma unroll
      for (int n = 0; n < 8; ++n) {
        f16x8 bf = *(const f16x8*)&BT[n*16 + lrow][kk + kgrp*8];
        sacc[n] = __builtin_amdgcn_mfma_f32_16x16x32_f16(afs, bf, sacc[n], 0, 0, 0);
      }
    }
    __syncthreads();
#pragma unroll
    for (int n = 0; n < 8; ++n)
#pragma unroll
      for (int r = 0; r < 4; ++r)
        Sl[wave*16 + kgrp*4 + r][n*16 + lrow] = sacc[n][r];
    __syncthreads();
    size_t sb = ((size_t)bc*NH + h)*8192;
#pragma unroll
    for (int i = 0; i < 4; ++i) {
      int idx = t + i*256; int p = idx >> 4, n8 = (idx & 15)*8;
      f16x8 o;
#pragma unroll
      for (int j = 0; j < 8; ++j) o[j] = (f16)Sl[p][n8 + j];
      *(f16x8*)(states + sb + (size_t)p*128 + n8) = o;
    }
  }
}

// ---------------- inter-chunk scan (in place, fp16 storage, fp32 carry) ----------------
__global__ __launch_bounds__(256)
void scan_kernel(f16* __restrict__ states, const float* __restrict__ Acum) {
  int bid = blockIdx.x;
  int bh = bid >> 3, pgrp = bid & 7;
  int b = bh >> 5, h = bh & 31;
  int t = threadIdx.x;
  int p = pgrp*8 + (t >> 5), n4 = (t & 31) * 4;
  size_t off = (size_t)p*128 + n4;
  f32x4 carry = {0.f, 0.f, 0.f, 0.f};
  for (int c = 0; c < NC; ++c) {
    size_t base = ((size_t)(b*NC + c)*NH + h)*8192;
    f16x4 cv = *(f16x4*)(states + base + off);
    f16x4 st;
#pragma unroll
    for (int j = 0; j < 4; ++j) st[j] = (f16)carry[j];
    *(f16x4*)(states + base + off) = st;
    float tc = __expf(Acum[((size_t)(b*NC + c)*NH + h)*64 + 63]);
#pragma unroll
    for (int j = 0; j < 4; ++j) carry[j] = carry[j]*tc + (float)cv[j];
  }
}

// ------- per (b,c,h): Y_diag + Y_off + D-skip + SiLU(z) gating, Ybuf written ONCE -------
// Fused RMS partial: per-(row,head) sum of gated y^2 -> psum (no atomics;
// psum lives OUTSIDE every buffer this kernel reads -> no cross-block race).
__global__ __launch_bounds__(256)
void yoff_kernel(const f16* __restrict__ xbc, const f16* __restrict__ zxh,
                 const f16* __restrict__ Gg, const f16* __restrict__ states,
                 const float* __restrict__ dtb, const float* __restrict__ Acum,
                 const float* __restrict__ Dp, f16* __restrict__ Ybuf,
                 float* __restrict__ psum) {
  __shared__ union {
    struct { f16 Gt[64][72]; f16 XdT[64][72]; } a;   // 18 KB (ydiag operands)
    struct { f16 Ch[64][136]; f16 Sin[64][136]; } b; // 34 KB (yoff operands)
    float Yl2[64][68];                               // 17 KB (yoff retile)
  } u;
  __shared__ float Yl[64][68];   // 17 KB, ydiag fp32, persists
  __shared__ float ac[64], dts[64], eac[64];
  int bc = blockIdx.x >> 5, h = blockIdx.x & 31;
  int row0 = bc*64, t = threadIdx.x;
  if (t < 64) {
    float a0 = Acum[((size_t)bc*NH + h)*64 + t];
    ac[t]  = a0;
    eac[t] = __expf(a0);
    dts[t] = dtb[(size_t)(row0 + t)*NH + h];
  }
  __syncthreads();
  // stage XdT[p][l] = x[l][p]*dt[l]
#pragma unroll
  for (int i = 0; i < 2; ++i) {
    int idx = t + i*256; int l = idx >> 3, p8 = (idx & 7)*8;
    f16x8 v = *(const f16x8*)(xbc + (size_t)(row0 + l)*CONVD + h*HD + p8);
    float d = dts[l];
#pragma unroll
    for (int j = 0; j < 8; ++j) u.a.XdT[p8 + j][l] = (f16)((float)v[j]*d);
  }
  // stage Gt[l][s] = (l>=s) ? G[l][s]*exp(ac[l]-ac[s]) : 0
#pragma unroll
  for (int i = 0; i < 2; ++i) {
    int idx = t + i*256; int l = idx >> 3, s8 = (idx & 7)*8;
    f16x8 g = *(const f16x8*)(Gg + (size_t)bc*4096 + l*64 + s8);
    float al = ac[l];
    f16x8 o;
#pragma unroll
    for (int j = 0; j < 8; ++j) {
      int s = s8 + j;
      o[j] = (l >= s) ? (f16)((float)g[j] * __expf(al - ac[s])) : (f16)0.f;
    }
    *(f16x8*)&u.a.Gt[l][s8] = o;
  }
  __syncthreads();
  int wave = t >> 6, lane = t & 63;
  int lrow = lane & 15, kgrp = lane >> 4;
  // ydiag MFMA: Y[l][p] = sum_s Gt[l][s] * Xd[s][p]
  f32x4 yacc[4] = {};
#pragma unroll
  for (int kk = 0; kk < 64; kk += 32) {
    f16x8 afy = *(const f16x8*)&u.a.Gt[wave*16 + lrow][kk + kgrp*8];
#pragma unroll
    for (int n = 0; n < 4; ++n) {
      f16x8 bf = *(const f16x8*)&u.a.XdT[n*16 + lrow][kk + kgrp*8];
      yacc[n] = __builtin_amdgcn_mfma_f32_16x16x32_f16(afy, bf, yacc[n], 0, 0, 0);
    }
  }
  __syncthreads();   // union.a reads done -> safe to reuse as union.b
  // retile ydiag into persistent fp32 Yl
#pragma unroll
  for (int n = 0; n < 4; ++n)
#pragma unroll
    for (int r = 0; r < 4; ++r)
      Yl[wave*16 + kgrp*4 + r][n*16 + lrow] = yacc[n][r];
  // stage Ch (C) and Sin (scanned states) into union.b
  size_t sb = ((size_t)bc*NH + h)*8192;
#pragma unroll
  for (int i = 0; i < 4; ++i) {
    int idx = t + i*256; int r = idx >> 4, c8 = (idx & 15)*8;
    *(f16x8*)&u.b.Ch[r][c8]  = *(const f16x8*)(xbc + (size_t)(row0 + r)*CONVD + COFF + c8);
    *(f16x8*)&u.b.Sin[r][c8] = *(const f16x8*)(states + sb + (size_t)r*128 + c8);
  }
  __syncthreads();
  // yoff MFMA: yoffraw[l][p] = sum_n C[l][n] * Sin[p][n]
  f32x4 acc[4] = {};
#pragma unroll
  for (int kk = 0; kk < 128; kk += 32) {
    f16x8 af = *(const f16x8*)&u.b.Ch[wave*16 + lrow][kk + kgrp*8];
#pragma unroll
    for (int n = 0; n < 4; ++n) {
      f16x8 bf = *(const f16x8*)&u.b.Sin[n*16 + lrow][kk + kgrp*8];
      acc[n] = __builtin_amdgcn_mfma_f32_16x16x32_f16(af, bf, acc[n], 0, 0, 0);
    }
  }
  __syncthreads();   // union.b reads done -> safe to reuse as Yl2
#pragma unroll
  for (int n = 0; n < 4; ++n)
#pragma unroll
    for (int r = 0; r < 4; ++r)
      u.Yl2[wave*16 + kgrp*4 + r][n*16 + lrow] = acc[n][r];
  __syncthreads();
  // epilogue: Y = (ydiag + eac*yoffraw + D*x) * silu(z); single Ybuf write
  // + per-row partial sum of y^2 (8 lanes share a row) -> psum[row][h]
  float Dh = Dp[h];
#pragma unroll
  for (int i = 0; i < 2; ++i) {
    int idx = t + i*256; int l = idx >> 3, p8 = (idx & 7)*8;
    int row = row0 + l;
    f16x8 zh = *(const f16x8*)(zxh + (size_t)row*NZ + h*HD + p8);
    f16x8 xs = *(const f16x8*)(xbc + (size_t)row*CONVD + h*HD + p8);
    float e = eac[l];
    f16x8 o;
    float ssl = 0.f;
#pragma unroll
    for (int j = 0; j < 8; ++j) {
      float yv = Yl[l][p8 + j] + e*u.Yl2[l][p8 + j] + (float)xs[j]*Dh;
      o[j] = (f16)(yv * silu_f((float)zh[j]));
      float y16 = (float)o[j];
      ssl += y16 * y16;
    }
    *(f16x8*)(Ybuf + (size_t)row*DIN + h*HD + p8) = o;
    ssl += __shfl_xor(ssl, 1);
    ssl += __shfl_xor(ssl, 2);
    ssl += __shfl_xor(ssl, 4);
    if ((t & 7) == 0) psum[(size_t)row*NH + h] = ssl;
  }
}

// ------- RMS finalize: scale[row] = rsqrt(mean over 32 head-partials + eps) -------
__global__ __launch_bounds__(256)
void rms_finalize_kernel(const float* __restrict__ psum, float* __restrict__ scale) {
  int row = blockIdx.x * 256 + threadIdx.x;
  const float* p = psum + (size_t)row*NH;
  float s = 0.f;
#pragma unroll
  for (int i = 0; i < 8; ++i) {
    f32x4 v = *(const f32x4*)(p + i*4);
    s += v[0] + v[1] + v[2] + v[3];
  }
  scale[row] = rsqrtf(s * (1.f/2048.f) + 1e-5f);
}

// ---------------- host launcher ----------------
extern "C" void kernel_launch(void* const* d_in, const int* in_sizes, int n_in,
                              void* d_out, int out_size, void* d_ws, size_t ws_size,
                              hipStream_t stream) {
  const float* x       = (const float*)d_in[0];
  const float* W_in    = (const float*)d_in[1];
  const float* conv_w  = (const float*)d_in[2];
  const float* conv_b  = (const float*)d_in[3];
  const float* dt_bias = (const float*)d_in[4];
  const float* A_log   = (const float*)d_in[5];
  const float* Dp      = (const float*)d_in[6];
  const float* norm_w  = (const float*)d_in[7];
  const float* W_out   = (const float*)d_in[8];

  constexpr size_t WS_NEED = 213909504;
  if (ws_size < WS_NEED) return;  // clean fail instead of OOB crash

  char* w = (char*)d_ws;
  // Layout audit (R20 race fix):
  //  states [0, 67108864)  — written by ssd_states, read by scan/yoff; dead after yoff
  //    overlays: winT [0, 8912896)         (dead after gemm1, before states written)
  //              xh   [33554432, 50331648) (dt->gemm1; dead before states written)
  //              woutT [33554432, 37748736) (written AFTER yoff by transpose — states dead)
  //              rscale [37748736, 37781504) (written by rms_finalize AFTER yoff — states dead)
  //  zxh  [67108864, 138412032) | xbcc [138412032, 176160768) | Ybuf [176160768, 209715200)
  //  dtb [209715200,...) | Acum [210763776,...) | Gg [211812352, 212860928)
  //  psum [212860928, 213909504) — OUTSIDE everything yoff reads (no race; written
  //    by yoff epilogue concurrently with other blocks' states/Gg/... reads)
  f16*   states = (f16*)(w + 0);
  f16*   winT   = (f16*)(w + 0);
  f16*   xh     = (f16*)(w + 33554432);
  f16*   woutT  = (f16*)(w + 33554432);
  float* rscale = (float*)(w + 37748736);
  f16*   zxh    = (f16*)(w + 67108864);
  f16*   xbcc   = (f16*)(w + 138412032);
  f16*   Ybuf   = (f16*)(w + 176160768);
  float* dtb    = (float*)(w + 209715200);
  float* Acum   = (float*)(w + 210763776);
  f16*   Gg     = (f16*)(w + 211812352);
  float* psum   = (float*)(w + 212860928);

  dt_kernel<<<MROWS/64, 512, 0, stream>>>(x, W_in, dt_bias, A_log, dtb, Acum, xh);
  transpose_f32_to_f16<<<dim3(NZ/32, DM/32), 256, 0, stream>>>(W_in, winT, DM, NZ, NPROJ, nullptr);
  gemm_t<256,128,4,2,true><<<(MROWS/256)*(NZ/128), 512, 0, stream>>>(xh, winT, zxh, MROWS, NZ, DM, NZ, nullptr);
  conv_kernel<<<MROWS*(CONVD/8)/256, 256, 0, stream>>>(zxh, conv_w, conv_b, xbcc);
  gbuf_kernel<<<BB*NC, 256, 0, stream>>>(xbcc, Gg);
  ssd_states_kernel<<<BB*NC*(NH/4), 256, 0, stream>>>(xbcc, dtb, Acum, states);
  scan_kernel<<<BB*NH*8, 256, 0, stream>>>(states, Acum);
  yoff_kernel<<<BB*NC*NH, 256, 0, stream>>>(xbcc, zxh, Gg, states, dtb, Acum, Dp, Ybuf, psum);
  transpose_f32_to_f16<<<dim3(DM/32, DIN/32), 256, 0, stream>>>(W_out, woutT, DIN, DM, DM, norm_w);
  rms_finalize_kernel<<<MROWS/256, 256, 0, stream>>>(psum, rscale);
  gemm_t<128,128,2,2,false><<<(MROWS/128)*(DM/128), 256, 0, stream>>>(Ybuf, woutT, d_out, MROWS, DM, DIN, DM, rscale);
}

// Round 22
// 384.000 us; speedup vs baseline: 1.0284x; 1.0058x over previous
//
#include <hip/hip_runtime.h>
#include <hip/hip_fp16.h>

typedef _Float16 f16;
typedef _Float16 f16x4 __attribute__((ext_vector_type(4)));
typedef _Float16 f16x8 __attribute__((ext_vector_type(8)));
typedef float f32x4 __attribute__((ext_vector_type(4)));

#define DEV __device__ __forceinline__

// ---- problem constants ----
constexpr int BB    = 2;
constexpr int LL    = 4096;
constexpr int DM    = 1024;
constexpr int DIN   = 2048;
constexpr int DST   = 128;
constexpr int NH    = 32;
constexpr int HD    = 64;
constexpr int NC    = 64;                  // chunks per batch
constexpr int MROWS = BB * LL;             // 8192
constexpr int NPROJ = 2*DIN + 2*DST + NH;  // 4384 (W_in row stride)
constexpr int NZ    = 2*DIN + 2*DST;       // 4352 (z + xBC, GEMM1 N)
constexpr int CONVD = DIN + 2*DST;         // 2304
constexpr int DT_OFF = 2*DIN + 2*DST;      // 4352
constexpr int BOFF  = DIN;                 // 2048 (within NZ / CONVD)
constexpr int COFF  = DIN + DST;           // 2176

DEV float silu_f(float v) { return v / (1.f + __expf(-v)); }

// wave-uniform LDS dest; HW writes lane i at dst + i*16B. Per-lane global src.
DEV void gload_lds16(const f16* gsrc, f16* lds_dst) {
  __builtin_amdgcn_global_load_lds(
      (const __attribute__((address_space(1))) void*)gsrc,
      (__attribute__((address_space(3))) void*)lds_dst, 16, 0, 0);
}

// ------------- transpose fp32[K rows][srcLd cols] -> fp16[N][K] -------------
// colScale (optional, size K): dst[n][k] = src[k][n] * colScale[k]
__global__ __launch_bounds__(256)
void transpose_f32_to_f16(const float* __restrict__ src, f16* __restrict__ dst,
                          int K, int N, int srcLd, const float* __restrict__ colScale) {
  __shared__ float tbuf[32][33];
  int n0 = blockIdx.x * 32, k0 = blockIdx.y * 32;
  int tx = threadIdx.x & 31, ty = threadIdx.x >> 5;  // 32 x 8
  for (int i = ty; i < 32; i += 8)
    tbuf[i][tx] = src[(size_t)(k0 + i)*srcLd + n0 + tx];
  __syncthreads();
  float cs = colScale ? colScale[k0 + tx] : 1.f;
  for (int i = ty; i < 32; i += 8)
    dst[(size_t)(n0 + i)*K + (k0 + tx)] = (f16)(tbuf[tx][i] * cs);
}

// ------- pipelined MFMA GEMM (R16 proven): C[M][ldc] = A[M][K] * Bt[N][K]^T -------
// 2-buffer LDS, boundary vmcnt(0)+barrier, stage(t+1) before compute(t).
// XCD-chunked swizzle. Optional rowScale. Plateau ~109us / 29.5% MfmaUtil.
template<int BM, int BN, int WM_, int WN_, bool C16>
__global__ __launch_bounds__(WM_*WN_*64, 2)
void gemm_t(const f16* __restrict__ A, const f16* __restrict__ Bt,
            void* __restrict__ Cp, int M, int N, int K, int ldc,
            const float* __restrict__ rowScale) {
  constexpr int THREADS = WM_*WN_*64;
  constexpr int WTM = BM/WM_, WTN = BN/WN_;
  constexpr int FM = WTM/16, FN = WTN/16;
  constexpr int LA = BM*4/THREADS, LB = BN*4/THREADS;  // 16B-chunk loads/thread
  __shared__ f16 As[2][BM*32];
  __shared__ f16 Bs[2][BN*32];
  const int nbn = N / BN;
  const int nwg = (int)gridDim.x;
  const int lb  = ((int)blockIdx.x & 7) * (nwg >> 3) + ((int)blockIdx.x >> 3);
  const int bm = lb / nbn, bn = lb % nbn;
  const int tid = threadIdx.x;
  const int wave = tid >> 6, lane = tid & 63;
  const int lrow = lane & 15, kgrp = lane >> 4;
  const int wm = wave / WN_, wn = wave % WN_;
  const int nt = K >> 5;
  const int bcol8 = (kgrp ^ ((lrow ^ (lrow >> 2)) & 3)) * 8;

  const f16* aptr[LA];
  const f16* bptr[LB];
#pragma unroll
  for (int i = 0; i < LA; ++i) {
    int s = tid + i*THREADS, row = s >> 2;
    int g = (s & 3) ^ ((row ^ (row >> 2)) & 3);
    aptr[i] = A + (size_t)(bm*BM + row)*K + g*8;
  }
#pragma unroll
  for (int i = 0; i < LB; ++i) {
    int s = tid + i*THREADS, row = s >> 2;
    int g = (s & 3) ^ ((row ^ (row >> 2)) & 3);
    bptr[i] = Bt + (size_t)(bn*BN + row)*K + g*8;
  }

  f32x4 acc[FM][FN] = {};

  auto STAGE = [&](int buf, int t) {
#pragma unroll
    for (int i = 0; i < LA; ++i)
      gload_lds16(aptr[i] + (size_t)t*32, As[buf] + (wave*64 + i*THREADS)*8);
#pragma unroll
    for (int i = 0; i < LB; ++i)
      gload_lds16(bptr[i] + (size_t)t*32, Bs[buf] + (wave*64 + i*THREADS)*8);
  };

  STAGE(0, 0);
  asm volatile("s_waitcnt vmcnt(0)" ::: "memory");
  __builtin_amdgcn_s_barrier();
  __builtin_amdgcn_sched_barrier(0);

  for (int t = 0; t < nt; ++t) {
    const int cur = t & 1;
    if (t + 1 < nt) STAGE(cur ^ 1, t + 1);
    const f16* Ab = As[cur];
    const f16* Bb = Bs[cur];
    f16x8 bf[FN];
#pragma unroll
    for (int n = 0; n < FN; ++n)
      bf[n] = *(const f16x8*)(Bb + (wn*WTN + n*16 + lrow)*32 + bcol8);
#pragma unroll
    for (int m = 0; m < FM; ++m) {
      f16x8 af = *(const f16x8*)(Ab + (wm*WTM + m*16 + lrow)*32 + bcol8);
#pragma unroll
      for (int n = 0; n < FN; ++n)
        acc[m][n] = __builtin_amdgcn_mfma_f32_16x16x32_f16(af, bf[n], acc[m][n], 0, 0, 0);
    }
    if (t + 1 < nt) {
      asm volatile("s_waitcnt vmcnt(0)" ::: "memory");
      __builtin_amdgcn_s_barrier();
      __builtin_amdgcn_sched_barrier(0);
    }
  }

  int crow0 = bm*BM + wm*WTM, ccol0 = bn*BN + wn*WTN;
#pragma unroll
  for (int m = 0; m < FM; ++m)
#pragma unroll
    for (int n = 0; n < FN; ++n) {
      int r0 = crow0 + m*16 + (lane >> 4)*4;
      int c0 = ccol0 + n*16 + (lane & 15);
#pragma unroll
      for (int r = 0; r < 4; ++r) {
        float v = acc[m][n][r];
        if (rowScale) v *= rowScale[r0 + r];
        if constexpr (C16) {
          f16* C = (f16*)Cp;
          C[(size_t)(r0 + r)*ldc + c0] = (f16)v;
        } else {
          float* C = (float*)Cp;
          C[(size_t)(r0 + r)*ldc + c0] = v;
        }
      }
    }
}

// ------- exact fp32 dt + fused per-chunk cumsum + fused x->f16 emit -------
// 512 threads (4 outputs/thread); grid 128 blocks (chunk-bound via cumsum).
__global__ __launch_bounds__(512)
void dt_kernel(const float* __restrict__ x, const float* __restrict__ Win,
               const float* __restrict__ dt_bias, const float* __restrict__ A_log,
               float* __restrict__ dt, float* __restrict__ Acum,
               f16* __restrict__ xh) {
  __shared__ float xs[64][132];
  __shared__ float ws[128][32];
  __shared__ float dts[64][32];
  int bc = blockIdx.x;
  int r0 = bc * 64;
  int t = threadIdx.x;           // 0..511
  int r = t >> 3;                // 0..63
  int c0 = (t & 7) * 4;          // 0..28
  float acc[4] = {};
  for (int kt = 0; kt < 1024; kt += 128) {
    __syncthreads();
#pragma unroll
    for (int i = 0; i < 4; ++i) {
      int idx4 = t + i*512;      // 0..2047 -> 64 rows x 32 col4-groups
      int rr = idx4 >> 5, c4 = (idx4 & 31) * 4;
      f32x4 xv4 = *(const f32x4*)(x + (size_t)(r0 + rr)*1024 + kt + c4);
      *(f32x4*)&xs[rr][c4] = xv4;
      f16x4 xo = {(f16)xv4[0], (f16)xv4[1], (f16)xv4[2], (f16)xv4[3]};
      *(f16x4*)(xh + (size_t)(r0 + rr)*1024 + kt + c4) = xo;
    }
#pragma unroll
    for (int i = 0; i < 2; ++i) {
      int idx4 = t + i*512;      // 0..1023 -> 128 rows x 8 col4-groups
      int rr = idx4 >> 3, c4 = (idx4 & 7) * 4;
      *(f32x4*)&ws[rr][c4] = *(const f32x4*)(Win + (size_t)(kt + rr)*NPROJ + DT_OFF + c4);
    }
    __syncthreads();
#pragma unroll 8
    for (int k = 0; k < 128; ++k) {
      float xv = xs[r][k];
      f32x4 w0 = *(const f32x4*)&ws[k][c0];
#pragma unroll
      for (int j = 0; j < 4; ++j) acc[j] += xv * w0[j];
    }
  }
#pragma unroll
  for (int j = 0; j < 4; ++j) {
    float v = acc[j] + dt_bias[c0 + j];
    float sp = (v > 20.f) ? v : log1pf(__expf(v));
    dt[(size_t)(r0 + r)*NH + c0 + j] = sp;
    dts[r][c0 + j] = sp;
  }
  __syncthreads();
  // fused acum: 8 waves x 4 heads, per-head inclusive cumsum over 64 rows
  int wave = t >> 6, lane = t & 63;
#pragma unroll
  for (int hh = 0; hh < 4; ++hh) {
    int h = wave*4 + hh;
    float A = -__expf(A_log[h]);
    float v = A * dts[lane][h];
#pragma unroll
    for (int off = 1; off < 64; off <<= 1) {
      float u = __shfl_up(v, off);
      if (lane >= off) v += u;
    }
    Acum[((size_t)bc*NH + h)*64 + lane] = v;
  }
}

// ---------------- causal depthwise conv (k=4) + bias + silu -> fp16 ----------------
__global__ __launch_bounds__(256)
void conv_kernel(const f16* __restrict__ zxh, const float* __restrict__ cw,
                 const float* __restrict__ cb, f16* __restrict__ out) {
  int i = blockIdx.x * 256 + threadIdx.x;      // MROWS * 288
  int row = i / (CONVD/8);
  int c8  = (i - row*(CONVD/8)) * 8;
  int lb = row & (LL - 1);
  f32x4 a0 = *(const f32x4*)(cb + c8);
  f32x4 a1 = *(const f32x4*)(cb + c8 + 4);
#pragma unroll
  for (int j = 0; j < 4; ++j) {
    int lsrc = lb - 3 + j;
    if (lsrc >= 0) {
      f16x8 v = *(const f16x8*)(zxh + (size_t)(row - 3 + j)*NZ + BOFF + c8);
      f32x4 w0 = *(const f32x4*)(cw + j*CONVD + c8);
      f32x4 w1 = *(const f32x4*)(cw + j*CONVD + c8 + 4);
#pragma unroll
      for (int jj = 0; jj < 4; ++jj) {
        a0[jj] += (float)v[jj]   * w0[jj];
        a1[jj] += (float)v[4+jj] * w1[jj];
      }
    }
  }
  f16x8 o;
#pragma unroll
  for (int jj = 0; jj < 4; ++jj) {
    o[jj]   = (f16)silu_f(a0[jj]);
    o[4+jj] = (f16)silu_f(a1[jj]);
  }
  *(f16x8*)(out + (size_t)row*CONVD + c8) = o;
}

// ---------------- G[bc][l][s] = sum_n C[l,n] * B[s,n] (head-independent, f16 out) ----------------
__global__ __launch_bounds__(256)
void gbuf_kernel(const f16* __restrict__ xbc, f16* __restrict__ G) {
  __shared__ float Cs[64][128];
  __shared__ float Bsm[64][128];
  int bc = blockIdx.x;
  int row0 = bc * 64;
  int t = threadIdx.x;
#pragma unroll
  for (int i = 0; i < 4; ++i) {
    int idx = t + i*256;
    int r = idx >> 4, c8 = (idx & 15) * 8;
    f16x8 cv = *(const f16x8*)(xbc + (size_t)(row0 + r)*CONVD + COFF + c8);
    f16x8 bv = *(const f16x8*)(xbc + (size_t)(row0 + r)*CONVD + BOFF + c8);
    f32x4 c0v = {(float)cv[0], (float)cv[1], (float)cv[2], (float)cv[3]};
    f32x4 c1v = {(float)cv[4], (float)cv[5], (float)cv[6], (float)cv[7]};
    f32x4 b0v = {(float)bv[0], (float)bv[1], (float)bv[2], (float)bv[3]};
    f32x4 b1v = {(float)bv[4], (float)bv[5], (float)bv[6], (float)bv[7]};
    *(f32x4*)&Cs[r][c8]      = c0v;  *(f32x4*)&Cs[r][c8 + 4]  = c1v;
    *(f32x4*)&Bsm[r][c8]     = b0v;  *(f32x4*)&Bsm[r][c8 + 4] = b1v;
  }
  __syncthreads();
  int l0 = (t >> 4)*4, s0 = (t & 15)*4;
  float acc[4][4] = {};
  for (int n4 = 0; n4 < 128; n4 += 4) {
    f32x4 cv[4], bv[4];
#pragma unroll
    for (int i = 0; i < 4; ++i) cv[i] = *(const f32x4*)&Cs[l0 + i][n4];
#pragma unroll
    for (int j = 0; j < 4; ++j) bv[j] = *(const f32x4*)&Bsm[s0 + j][n4];
#pragma unroll
    for (int i = 0; i < 4; ++i)
#pragma unroll
      for (int j = 0; j < 4; ++j)
        acc[i][j] += cv[i][0]*bv[j][0] + cv[i][1]*bv[j][1] + cv[i][2]*bv[j][2] + cv[i][3]*bv[j][3];
  }
#pragma unroll
  for (int i = 0; i < 4; ++i) {
    f16x4 v = {(f16)acc[i][0], (f16)acc[i][1], (f16)acc[i][2], (f16)acc[i][3]};
    *(f16x4*)(G + ((size_t)bc*64 + l0 + i)*64 + s0) = v;
  }
}

// ------- per (bc, head-group of 4): chunk states (MFMA), raw B staged ONCE -------
__global__ __launch_bounds__(256)
void ssd_states_kernel(const f16* __restrict__ xbc, const float* __restrict__ dtb,
                       const float* __restrict__ Acum, f16* __restrict__ states) {
  __shared__ f16 BT[128][72];
  __shared__ f16 XdT[64][72];
  __shared__ float Sl[64][132];
  __shared__ float ac[64], dts[64];
  int bc = blockIdx.x >> 3, hg = blockIdx.x & 7;
  int row0 = bc*64, t = threadIdx.x;
  int wave = t >> 6, lane = t & 63;
  int lrow = lane & 15, kgrp = lane >> 4;
#pragma unroll
  for (int i = 0; i < 4; ++i) {
    int idx = t + i*256; int l = idx >> 4, n8 = (idx & 15)*8;
    f16x8 v = *(const f16x8*)(xbc + (size_t)(row0 + l)*CONVD + BOFF + n8);
#pragma unroll
    for (int j = 0; j < 8; ++j) BT[n8 + j][l] = v[j];
  }
  for (int hh = 0; hh < 4; ++hh) {
    int h = hg*4 + hh;
    __syncthreads();
    if (t < 64) {
      ac[t]  = Acum[((size_t)bc*NH + h)*64 + t];
      dts[t] = dtb[(size_t)(row0 + t)*NH + h];
    }
    __syncthreads();
    float ac63 = ac[63];
#pragma unroll
    for (int i = 0; i < 2; ++i) {
      int idx = t + i*256; int l = idx >> 3, p8 = (idx & 7)*8;
      f16x8 v = *(const f16x8*)(xbc + (size_t)(row0 + l)*CONVD + h*HD + p8);
      float d = dts[l] * __expf(ac63 - ac[l]);
#pragma unroll
      for (int j = 0; j < 8; ++j) XdT[p8 + j][l] = (f16)((float)v[j]*d);
    }
    __syncthreads();
    f32x4 sacc[8] = {};
#pragma unroll
    for (int kk = 0; kk < 64; kk += 32) {
      f16x8 afs = *(const f16x8*)&XdT[wave*16 + lrow][kk + kgrp*8];
#pragma unroll
      for (int n = 0; n < 8; ++n) {
        f16x8 bf = *(const f16x8*)&BT[n*16 + lrow][kk + kgrp*8];
        sacc[n] = __builtin_amdgcn_mfma_f32_16x16x32_f16(afs, bf, sacc[n], 0, 0, 0);
      }
    }
    __syncthreads();
#pragma unroll
    for (int n = 0; n < 8; ++n)
#pragma unroll
      for (int r = 0; r < 4; ++r)
        Sl[wave*16 + kgrp*4 + r][n*16 + lrow] = sacc[n][r];
    __syncthreads();
    size_t sb = ((size_t)bc*NH + h)*8192;
#pragma unroll
    for (int i = 0; i < 4; ++i) {
      int idx = t + i*256; int p = idx >> 4, n8 = (idx & 15)*8;
      f16x8 o;
#pragma unroll
      for (int j = 0; j < 8; ++j) o[j] = (f16)Sl[p][n8 + j];
      *(f16x8*)(states + sb + (size_t)p*128 + n8) = o;
    }
  }
}

// -------- inter-chunk scan: tc preloaded in LDS + 4-deep load prefetch --------
// Chain per step collapses to store-issue + 2 VALU (loads 4 iterations ahead).
__global__ __launch_bounds__(256)
void scan_kernel(f16* __restrict__ states, const float* __restrict__ Acum) {
  __shared__ float tcs[64];
  int bid = blockIdx.x;
  int bh = bid >> 3, pgrp = bid & 7;
  int b = bh >> 5, h = bh & 31;
  int t = threadIdx.x;
  if (t < 64)
    tcs[t] = __expf(Acum[((size_t)(b*NC + t)*NH + h)*64 + 63]);
  __syncthreads();
  int p = pgrp*8 + (t >> 5), n4 = (t & 31) * 4;
  f16* bp = states + ((size_t)b*NC*NH + h)*8192 + (size_t)p*128 + n4;
  const size_t cs = (size_t)NH*8192;
  f32x4 carry = {0.f, 0.f, 0.f, 0.f};
  f16x4 v0 = *(f16x4*)(bp);
  f16x4 v1 = *(f16x4*)(bp + cs);
  f16x4 v2 = *(f16x4*)(bp + 2*cs);
  f16x4 v3 = *(f16x4*)(bp + 3*cs);
  for (int c = 0; c < NC; c += 4) {
    f16x4 st;
#pragma unroll
    for (int j = 0; j < 4; ++j) st[j] = (f16)carry[j];
    *(f16x4*)(bp + (size_t)c*cs) = st;
    float tc = tcs[c];
#pragma unroll
    for (int j = 0; j < 4; ++j) carry[j] = carry[j]*tc + (float)v0[j];
    if (c + 4 < NC) v0 = *(f16x4*)(bp + (size_t)(c + 4)*cs);

#pragma unroll
    for (int j = 0; j < 4; ++j) st[j] = (f16)carry[j];
    *(f16x4*)(bp + (size_t)(c + 1)*cs) = st;
    tc = tcs[c + 1];
#pragma unroll
    for (int j = 0; j < 4; ++j) carry[j] = carry[j]*tc + (float)v1[j];
    if (c + 5 < NC) v1 = *(f16x4*)(bp + (size_t)(c + 5)*cs);

#pragma unroll
    for (int j = 0; j < 4; ++j) st[j] = (f16)carry[j];
    *(f16x4*)(bp + (size_t)(c + 2)*cs) = st;
    tc = tcs[c + 2];
#pragma unroll
    for (int j = 0; j < 4; ++j) carry[j] = carry[j]*tc + (float)v2[j];
    if (c + 6 < NC) v2 = *(f16x4*)(bp + (size_t)(c + 6)*cs);

#pragma unroll
    for (int j = 0; j < 4; ++j) st[j] = (f16)carry[j];
    *(f16x4*)(bp + (size_t)(c + 3)*cs) = st;
    tc = tcs[c + 3];
#pragma unroll
    for (int j = 0; j < 4; ++j) carry[j] = carry[j]*tc + (float)v3[j];
    if (c + 7 < NC) v3 = *(f16x4*)(bp + (size_t)(c + 7)*cs);
  }
}

// ------- per (b,c,h): Y_diag + Y_off + D-skip + SiLU(z) gating, Ybuf written ONCE -------
// Fused RMS partial -> psum (race-audited placement). T14: Ch/Sin global loads
// issued EARLY into registers (return hidden under ydiag MFMA), LDS-written late.
__global__ __launch_bounds__(256)
void yoff_kernel(const f16* __restrict__ xbc, const f16* __restrict__ zxh,
                 const f16* __restrict__ Gg, const f16* __restrict__ states,
                 const float* __restrict__ dtb, const float* __restrict__ Acum,
                 const float* __restrict__ Dp, f16* __restrict__ Ybuf,
                 float* __restrict__ psum) {
  __shared__ union {
    struct { f16 Gt[64][72]; f16 XdT[64][72]; } a;   // 18 KB (ydiag operands)
    struct { f16 Ch[64][136]; f16 Sin[64][136]; } b; // 34 KB (yoff operands)
    float Yl2[64][68];                               // 17 KB (yoff retile)
  } u;
  __shared__ float Yl[64][68];   // 17 KB, ydiag fp32, persists
  __shared__ float ac[64], dts[64], eac[64];
  int bc = blockIdx.x >> 5, h = blockIdx.x & 31;
  int row0 = bc*64, t = threadIdx.x;
  if (t < 64) {
    float a0 = Acum[((size_t)bc*NH + h)*64 + t];
    ac[t]  = a0;
    eac[t] = __expf(a0);
    dts[t] = dtb[(size_t)(row0 + t)*NH + h];
  }
  __syncthreads();
  // T14 early-issue: Ch/Sin -> registers (consumed after ydiag phase)
  size_t sb = ((size_t)bc*NH + h)*8192;
  f16x8 chv[4], snv[4];
#pragma unroll
  for (int i = 0; i < 4; ++i) {
    int idx = t + i*256; int r = idx >> 4, c8 = (idx & 15)*8;
    chv[i] = *(const f16x8*)(xbc + (size_t)(row0 + r)*CONVD + COFF + c8);
    snv[i] = *(const f16x8*)(states + sb + (size_t)r*128 + c8);
  }
  // stage XdT[p][l] = x[l][p]*dt[l]
#pragma unroll
  for (int i = 0; i < 2; ++i) {
    int idx = t + i*256; int l = idx >> 3, p8 = (idx & 7)*8;
    f16x8 v = *(const f16x8*)(xbc + (size_t)(row0 + l)*CONVD + h*HD + p8);
    float d = dts[l];
#pragma unroll
    for (int j = 0; j < 8; ++j) u.a.XdT[p8 + j][l] = (f16)((float)v[j]*d);
  }
  // stage Gt[l][s] = (l>=s) ? G[l][s]*exp(ac[l]-ac[s]) : 0
#pragma unroll
  for (int i = 0; i < 2; ++i) {
    int idx = t + i*256; int l = idx >> 3, s8 = (idx & 7)*8;
    f16x8 g = *(const f16x8*)(Gg + (size_t)bc*4096 + l*64 + s8);
    float al = ac[l];
    f16x8 o;
#pragma unroll
    for (int j = 0; j < 8; ++j) {
      int s = s8 + j;
      o[j] = (l >= s) ? (f16)((float)g[j] * __expf(al - ac[s])) : (f16)0.f;
    }
    *(f16x8*)&u.a.Gt[l][s8] = o;
  }
  __syncthreads();
  int wave = t >> 6, lane = t & 63;
  int lrow = lane & 15, kgrp = lane >> 4;
  // ydiag MFMA: Y[l][p] = sum_s Gt[l][s] * Xd[s][p]
  f32x4 yacc[4] = {};
#pragma unroll
  for (int kk = 0; kk < 64; kk += 32) {
    f16x8 afy = *(const f16x8*)&u.a.Gt[wave*16 + lrow][kk + kgrp*8];
#pragma unroll
    for (int n = 0; n < 4; ++n) {
      f16x8 bf = *(const f16x8*)&u.a.XdT[n*16 + lrow][kk + kgrp*8];
      yacc[n] = __builtin_amdgcn_mfma_f32_16x16x32_f16(afy, bf, yacc[n], 0, 0, 0);
    }
  }
  __syncthreads();   // union.a reads done -> safe to reuse as union.b
  // retile ydiag into persistent fp32 Yl
#pragma unroll
  for (int n = 0; n < 4; ++n)
#pragma unroll
    for (int r = 0; r < 4; ++r)
      Yl[wave*16 + kgrp*4 + r][n*16 + lrow] = yacc[n][r];
  // write pre-loaded Ch/Sin into union.b (loads returned during ydiag)
#pragma unroll
  for (int i = 0; i < 4; ++i) {
    int idx = t + i*256; int r = idx >> 4, c8 = (idx & 15)*8;
    *(f16x8*)&u.b.Ch[r][c8]  = chv[i];
    *(f16x8*)&u.b.Sin[r][c8] = snv[i];
  }
  __syncthreads();
  // yoff MFMA: yoffraw[l][p] = sum_n C[l][n] * Sin[p][n]
  f32x4 acc[4] = {};
#pragma unroll
  for (int kk = 0; kk < 128; kk += 32) {
    f16x8 af = *(const f16x8*)&u.b.Ch[wave*16 + lrow][kk + kgrp*8];
#pragma unroll
    for (int n = 0; n < 4; ++n) {
      f16x8 bf = *(const f16x8*)&u.b.Sin[n*16 + lrow][kk + kgrp*8];
      acc[n] = __builtin_amdgcn_mfma_f32_16x16x32_f16(af, bf, acc[n], 0, 0, 0);
    }
  }
  __syncthreads();   // union.b reads done -> safe to reuse as Yl2
#pragma unroll
  for (int n = 0; n < 4; ++n)
#pragma unroll
    for (int r = 0; r < 4; ++r)
      u.Yl2[wave*16 + kgrp*4 + r][n*16 + lrow] = acc[n][r];
  __syncthreads();
  // epilogue: Y = (ydiag + eac*yoffraw + D*x) * silu(z); single Ybuf write
  // + per-row partial sum of y^2 (8 lanes share a row) -> psum[row][h]
  float Dh = Dp[h];
#pragma unroll
  for (int i = 0; i < 2; ++i) {
    int idx = t + i*256; int l = idx >> 3, p8 = (idx & 7)*8;
    int row = row0 + l;
    f16x8 zh = *(const f16x8*)(zxh + (size_t)row*NZ + h*HD + p8);
    f16x8 xs = *(const f16x8*)(xbc + (size_t)row*CONVD + h*HD + p8);
    float e = eac[l];
    f16x8 o;
    float ssl = 0.f;
#pragma unroll
    for (int j = 0; j < 8; ++j) {
      float yv = Yl[l][p8 + j] + e*u.Yl2[l][p8 + j] + (float)xs[j]*Dh;
      o[j] = (f16)(yv * silu_f((float)zh[j]));
      float y16 = (float)o[j];
      ssl += y16 * y16;
    }
    *(f16x8*)(Ybuf + (size_t)row*DIN + h*HD + p8) = o;
    ssl += __shfl_xor(ssl, 1);
    ssl += __shfl_xor(ssl, 2);
    ssl += __shfl_xor(ssl, 4);
    if ((t & 7) == 0) psum[(size_t)row*NH + h] = ssl;
  }
}

// ------- RMS finalize: scale[row] = rsqrt(mean over 32 head-partials + eps) -------
__global__ __launch_bounds__(256)
void rms_finalize_kernel(const float* __restrict__ psum, float* __restrict__ scale) {
  int row = blockIdx.x * 256 + threadIdx.x;
  const float* p = psum + (size_t)row*NH;
  float s = 0.f;
#pragma unroll
  for (int i = 0; i < 8; ++i) {
    f32x4 v = *(const f32x4*)(p + i*4);
    s += v[0] + v[1] + v[2] + v[3];
  }
  scale[row] = rsqrtf(s * (1.f/2048.f) + 1e-5f);
}

// ---------------- host launcher ----------------
extern "C" void kernel_launch(void* const* d_in, const int* in_sizes, int n_in,
                              void* d_out, int out_size, void* d_ws, size_t ws_size,
                              hipStream_t stream) {
  const float* x       = (const float*)d_in[0];
  const float* W_in    = (const float*)d_in[1];
  const float* conv_w  = (const float*)d_in[2];
  const float* conv_b  = (const float*)d_in[3];
  const float* dt_bias = (const float*)d_in[4];
  const float* A_log   = (const float*)d_in[5];
  const float* Dp      = (const float*)d_in[6];
  const float* norm_w  = (const float*)d_in[7];
  const float* W_out   = (const float*)d_in[8];

  constexpr size_t WS_NEED = 213909504;
  if (ws_size < WS_NEED) return;  // clean fail instead of OOB crash

  char* w = (char*)d_ws;
  // Layout (race-audited R20/R21):
  //  states [0, 67108864) — overlays: winT [0,8912896) (pre-gemm1), xh
  //  [33554432,50331648) (pre-states), woutT [33554432,37748736) (post-yoff),
  //  rscale [37748736,...) (post-yoff). zxh | xbcc | Ybuf | dtb | Acum | Gg.
  //  psum [212860928, 213909504) — outside everything yoff reads.
  f16*   states = (f16*)(w + 0);
  f16*   winT   = (f16*)(w + 0);
  f16*   xh     = (f16*)(w + 33554432);
  f16*   woutT  = (f16*)(w + 33554432);
  float* rscale = (float*)(w + 37748736);
  f16*   zxh    = (f16*)(w + 67108864);
  f16*   xbcc   = (f16*)(w + 138412032);
  f16*   Ybuf   = (f16*)(w + 176160768);
  float* dtb    = (float*)(w + 209715200);
  float* Acum   = (float*)(w + 210763776);
  f16*   Gg     = (f16*)(w + 211812352);
  float* psum   = (float*)(w + 212860928);

  dt_kernel<<<MROWS/64, 512, 0, stream>>>(x, W_in, dt_bias, A_log, dtb, Acum, xh);
  transpose_f32_to_f16<<<dim3(NZ/32, DM/32), 256, 0, stream>>>(W_in, winT, DM, NZ, NPROJ, nullptr);
  gemm_t<256,128,4,2,true><<<(MROWS/256)*(NZ/128), 512, 0, stream>>>(xh, winT, zxh, MROWS, NZ, DM, NZ, nullptr);
  conv_kernel<<<MROWS*(CONVD/8)/256, 256, 0, stream>>>(zxh, conv_w, conv_b, xbcc);
  gbuf_kernel<<<BB*NC, 256, 0, stream>>>(xbcc, Gg);
  ssd_states_kernel<<<BB*NC*(NH/4), 256, 0, stream>>>(xbcc, dtb, Acum, states);
  scan_kernel<<<BB*NH*8, 256, 0, stream>>>(states, Acum);
  yoff_kernel<<<BB*NC*NH, 256, 0, stream>>>(xbcc, zxh, Gg, states, dtb, Acum, Dp, Ybuf, psum);
  transpose_f32_to_f16<<<dim3(DM/32, DIN/32), 256, 0, stream>>>(W_out, woutT, DIN, DM, DM, norm_w);
  rms_finalize_kernel<<<MROWS/256, 256, 0, stream>>>(psum, rscale);
  gemm_t<128,128,2,2,false><<<(MROWS/128)*(DM/128), 256, 0, stream>>>(Ybuf, woutT, d_out, MROWS, DM, DIN, DM, rscale);
}